// Round 11
// baseline (402.993 us; speedup 1.0000x reference)
//
#include <hip/hip_runtime.h>
#include <hip/hip_bf16.h>
#include <cstdint>
#include <cstddef>

// Shapes fixed: B=64, N=1024, D=512, S=16, 3 iterations.
// Algebra: logits = sn·W'·x^T, W' = scale·Wq^T·Wk   (k never materialized)
//          ax = attn·x;  upd@Wih^T = ax@(Wih·Wv)^T  (v never materialized)
// Round 11: update_k fuses GRU+LN+mlp1+mlp2+LN(slots)+q2 (one dispatch/iter).

typedef __bf16 bf16x8 __attribute__((ext_vector_type(8)));
typedef float f32x4 __attribute__((ext_vector_type(4)));

__device__ __forceinline__ float bf2f(unsigned int u) {
  union { unsigned int i; float f; } v; v.i = u << 16; return v.f;
}
__device__ __forceinline__ unsigned short f2bf(float x) {
  __hip_bfloat16 h = __float2bfloat16(x);
  unsigned short u;
  __builtin_memcpy(&u, &h, 2);
  return u;
}

#define GLD16(gp, lp)                                                       \
  __builtin_amdgcn_global_load_lds(                                         \
      (const __attribute__((address_space(1))) void*)(gp),                  \
      (__attribute__((address_space(3))) void*)(lp), 16, 0, 0)

// ---------------- merged prep (segmented grid) ----------------

__global__ void wprep_k(const float* __restrict__ w1, const float* __restrict__ w2,
                        const float* __restrict__ wih, const float* __restrict__ whh,
                        const float* __restrict__ bih, const float* __restrict__ bhh,
                        const float* __restrict__ mu, const float* __restrict__ ls,
                        const float* __restrict__ noise,
                        unsigned short* __restrict__ w1_bf, unsigned short* __restrict__ w2_bf,
                        unsigned short* __restrict__ wih_bf, unsigned short* __restrict__ wcat,
                        float* __restrict__ bcat, float* __restrict__ slots) {
  int blk = blockIdx.x, t = threadIdx.x;
  if (blk < 1024) {
    int i = blk * 256 + t; w1_bf[i] = f2bf(w1[i]);
  } else if (blk < 2048) {
    int i = (blk - 1024) * 256 + t; w2_bf[i] = f2bf(w2[i]);
  } else if (blk < 5120) {
    int i = (blk - 2048) * 256 + t; wih_bf[i] = f2bf(wih[i]);
  } else if (blk < 7168) {
    int i = (blk - 5120) * 256 + t;  // rows 0..1024 right half
    int j = i >> 9, d = i & 511;
    wcat[(size_t)j * 1024 + 512 + d] = f2bf(whh[(size_t)j * 512 + d]);
  } else if (blk < 8192) {
    int i = (blk - 7168) * 256 + t;  // rows 1536..2048 right half
    int j = i >> 9, d = i & 511;
    wcat[(size_t)(1536 + j) * 1024 + 512 + d] = f2bf(whh[(size_t)(1024 + j) * 512 + d]);
  } else if (blk < 10240) {
    int i = (blk - 8192) * 256 + t;  // zeros
    if (i < 262144) {
      int j = i >> 9, d = i & 511;
      wcat[(size_t)(1536 + j) * 1024 + d] = 0;
    } else {
      int k = i - 262144;
      int j = k >> 9, d = k & 511;
      wcat[(size_t)(1024 + j) * 1024 + 512 + d] = 0;
    }
  } else if (blk < 10248) {
    int j = (blk - 10240) * 256 + t;  // 2048
    float v;
    if (j < 1024)      v = bih[j] + bhh[j];
    else if (j < 1536) v = bih[j];
    else               v = bhh[j - 512];
    bcat[j] = v;
  } else {
    int i = (blk - 10248) * 256 + t;  // 524288
    int d = i & 511;
    slots[i] = mu[d] + expf(ls[d]) * noise[i];
  }
}

// transpose + cast Wq, Wk, Wv: grid (16,16,3)
__global__ __launch_bounds__(256) void tcast3_k(const float* __restrict__ Wq,
                                                const float* __restrict__ Wk,
                                                const float* __restrict__ Wv,
                                                unsigned short* __restrict__ wqT,
                                                unsigned short* __restrict__ wkT,
                                                unsigned short* __restrict__ wvT) {
  __shared__ float tt[32][33];
  const float* in = blockIdx.z == 0 ? Wq : (blockIdx.z == 1 ? Wk : Wv);
  unsigned short* out = blockIdx.z == 0 ? wqT : (blockIdx.z == 1 ? wkT : wvT);
  int c0 = blockIdx.x << 5, r0 = blockIdx.y << 5;
  int tx = threadIdx.x & 31, ty = threadIdx.x >> 5;
  #pragma unroll
  for (int i = 0; i < 4; ++i)
    tt[ty + 8 * i][tx] = in[(size_t)(r0 + ty + 8 * i) * 512 + c0 + tx];
  __syncthreads();
  #pragma unroll
  for (int i = 0; i < 4; ++i)
    out[(size_t)(c0 + ty + 8 * i) * 512 + r0 + tx] = f2bf(tt[tx][ty + 8 * i]);
}

// ---------------- layernorm inputs (wave per row, D=512) ----------------

__global__ __launch_bounds__(256) void ln_rows_k(
    const float* __restrict__ in, const float* __restrict__ g, const float* __restrict__ b,
    unsigned short* __restrict__ out, int rows) {
  int w = threadIdx.x >> 6, lane = threadIdx.x & 63;
  int row = (blockIdx.x << 2) + w;
  if (row >= rows) return;
  const float4* rp = reinterpret_cast<const float4*>(in + (size_t)row * 512);
  float4 v0 = rp[lane], v1 = rp[lane + 64];
  float s = v0.x + v0.y + v0.z + v0.w + v1.x + v1.y + v1.z + v1.w;
  float q = v0.x*v0.x + v0.y*v0.y + v0.z*v0.z + v0.w*v0.w
          + v1.x*v1.x + v1.y*v1.y + v1.z*v1.z + v1.w*v1.w;
  #pragma unroll
  for (int o = 32; o > 0; o >>= 1) { s += __shfl_xor(s, o); q += __shfl_xor(q, o); }
  float m = s * (1.0f / 512.0f);
  float rstd = rsqrtf(q * (1.0f / 512.0f) - m * m + 1e-8f);
  const float4* gp = reinterpret_cast<const float4*>(g);
  const float4* bp = reinterpret_cast<const float4*>(b);
  float4 g0 = gp[lane], g1 = gp[lane + 64];
  float4 b0 = bp[lane], b1 = bp[lane + 64];
  ushort4 o0, o1;
  o0.x = f2bf((v0.x - m) * rstd * g0.x + b0.x);
  o0.y = f2bf((v0.y - m) * rstd * g0.y + b0.y);
  o0.z = f2bf((v0.z - m) * rstd * g0.z + b0.z);
  o0.w = f2bf((v0.w - m) * rstd * g0.w + b0.w);
  o1.x = f2bf((v1.x - m) * rstd * g1.x + b1.x);
  o1.y = f2bf((v1.y - m) * rstd * g1.y + b1.y);
  o1.z = f2bf((v1.z - m) * rstd * g1.z + b1.z);
  o1.w = f2bf((v1.w - m) * rstd * g1.w + b1.w);
  ushort4* op = reinterpret_cast<ushort4*>(out + (size_t)row * 512);
  op[lane] = o0; op[lane + 64] = o1;
}

// ---------------- xT[b][e][n] = x_bf[b*1024+n][e] ----------------

__global__ __launch_bounds__(256) void xt_k(const unsigned short* __restrict__ x,
                                            unsigned short* __restrict__ xT) {
  __shared__ unsigned short t[64][68];
  int nt = blockIdx.x, et = blockIdx.y, b = blockIdx.z;
  int r = threadIdx.x >> 3, c8 = (threadIdx.x & 7) << 3;
  #pragma unroll
  for (int p = 0; p < 2; ++p) {
    int row = r + (p << 5);
    *reinterpret_cast<uint4*>(&t[row][c8]) = *reinterpret_cast<const uint4*>(
        x + ((size_t)(b << 10) + (nt << 6) + row) * 512 + (et << 6) + c8);
  }
  __syncthreads();
  #pragma unroll
  for (int p = 0; p < 2; ++p) {
    int erow = r + (p << 5);
    ushort4 a, bb;
    #pragma unroll
    for (int j = 0; j < 4; ++j) ((unsigned short*)&a)[j] = t[c8 + j][erow];
    #pragma unroll
    for (int j = 0; j < 4; ++j) ((unsigned short*)&bb)[j] = t[c8 + 4 + j][erow];
    unsigned short* o = xT + ((size_t)(b << 9) + (et << 6) + erow) * 1024 + (nt << 6) + c8;
    *reinterpret_cast<ushort4*>(o) = a;
    *reinterpret_cast<ushort4*>(o + 4) = bb;
  }
}

// ---------------- gemm_cat: wcat[j][0..512) = bf16(wih @ Wv), ldc=1024, BK=64 ----------------

__global__ __launch_bounds__(256) void gemm_cat(
    const unsigned short* __restrict__ A, const unsigned short* __restrict__ W,
    unsigned short* __restrict__ Cout, int M, int N, int K, int ldc) {
  __shared__ unsigned short sA[2][8192];
  __shared__ unsigned short sB[2][8192];
  const int tid = threadIdx.x;
  const int lane = tid & 63, w = tid >> 6;

  int nwg = gridDim.x * gridDim.y;
  int flat = blockIdx.y * gridDim.x + blockIdx.x;
  if ((nwg & 7) == 0) { int c = nwg >> 3; flat = (flat & 7) * c + (flat >> 3); }
  const int row0 = (flat / gridDim.x) << 7;
  const int col0 = (flat % gridDim.x) << 7;

  const int wm = (w >> 1) << 6, wn = (w & 1) << 6;
  const int lrow = lane & 15, kt = (lane >> 4) << 3;
  const int sr8 = lane >> 3, sc8 = (lane & 7) << 3;

  f32x4 acc[4][4];
  #pragma unroll
  for (int m = 0; m < 4; ++m)
    #pragma unroll
    for (int n = 0; n < 4; ++n) acc[m][n] = f32x4{0.f, 0.f, 0.f, 0.f};

  auto stage = [&](int buf, int k0) {
    #pragma unroll
    for (int i = 0; i < 4; ++i) {
      int ii = (w << 2) + i;
      int r = (ii << 3) + sr8;
      GLD16(A + (size_t)(row0 + r) * K + k0 + sc8, &sA[buf][ii * 512]);
      GLD16(W + (size_t)(col0 + r) * K + k0 + sc8, &sB[buf][ii * 512]);
    }
  };

  stage(0, 0);
  const int nt = K >> 6;
  int cur = 0;
  for (int t = 0; t < nt; ++t) {
    __syncthreads();
    if (t + 1 < nt) stage(cur ^ 1, (t + 1) << 6);
    #pragma unroll
    for (int kk = 0; kk < 2; ++kk) {
      bf16x8 af[4], bfv[4];
      #pragma unroll
      for (int m = 0; m < 4; ++m)
        af[m] = *reinterpret_cast<const bf16x8*>(&sA[cur][(wm + m * 16 + lrow) * 64 + (kk << 5) + kt]);
      #pragma unroll
      for (int n = 0; n < 4; ++n)
        bfv[n] = *reinterpret_cast<const bf16x8*>(&sB[cur][(wn + n * 16 + lrow) * 64 + (kk << 5) + kt]);
      #pragma unroll
      for (int m = 0; m < 4; ++m)
        #pragma unroll
        for (int n = 0; n < 4; ++n)
          acc[m][n] = __builtin_amdgcn_mfma_f32_16x16x32_bf16(af[m], bfv[n], acc[m][n], 0, 0, 0);
    }
    cur ^= 1;
  }

  const int rb = (lane >> 4) << 2;
  #pragma unroll
  for (int m = 0; m < 4; ++m) {
    #pragma unroll
    for (int n = 0; n < 4; ++n) {
      int col = col0 + wn + n * 16 + lrow;
      #pragma unroll
      for (int r = 0; r < 4; ++r) {
        int row = row0 + wm + m * 16 + rb + r;
        Cout[(size_t)row * ldc + col] = f2bf(acc[m][n][r]);
      }
    }
  }
}

// ---------------- q2ln (pre-loop seed): LN(slots_b) in LDS, q2 = sn @ W' ----------------

__global__ __launch_bounds__(256) void q2ln_k(
    const float* __restrict__ slots, const float* __restrict__ g, const float* __restrict__ b,
    const unsigned short* __restrict__ wpt, unsigned short* __restrict__ q2,
    unsigned short* __restrict__ A2) {
  __shared__ unsigned short s_sn[16 * 520];
  __shared__ unsigned short sB[2][8192];
  const int b_ = blockIdx.y, ct = blockIdx.x;
  const int lane = threadIdx.x & 63, w = threadIdx.x >> 6;
  const int lrow = lane & 15, kt = (lane >> 4) << 3;
  const int sr8 = lane >> 3, sc8 = (lane & 7) << 3;

  const float4* gp = reinterpret_cast<const float4*>(g);
  const float4* bp = reinterpret_cast<const float4*>(b);
  float4 g0 = gp[lane], g1 = gp[lane + 64];
  float4 b0 = bp[lane], b1 = bp[lane + 64];
  #pragma unroll
  for (int rr = 0; rr < 4; ++rr) {
    int r = w * 4 + rr;
    const float4* rp = reinterpret_cast<const float4*>(slots + (size_t)(b_ * 16 + r) * 512);
    float4 v0 = rp[lane], v1 = rp[lane + 64];
    float s = v0.x + v0.y + v0.z + v0.w + v1.x + v1.y + v1.z + v1.w;
    float q = v0.x*v0.x + v0.y*v0.y + v0.z*v0.z + v0.w*v0.w
            + v1.x*v1.x + v1.y*v1.y + v1.z*v1.z + v1.w*v1.w;
    #pragma unroll
    for (int o = 32; o > 0; o >>= 1) { s += __shfl_xor(s, o); q += __shfl_xor(q, o); }
    float m = s * (1.0f / 512.0f);
    float rstd = rsqrtf(q * (1.0f / 512.0f) - m * m + 1e-8f);
    ushort4 o0, o1;
    o0.x = f2bf((v0.x - m) * rstd * g0.x + b0.x);
    o0.y = f2bf((v0.y - m) * rstd * g0.y + b0.y);
    o0.z = f2bf((v0.z - m) * rstd * g0.z + b0.z);
    o0.w = f2bf((v0.w - m) * rstd * g0.w + b0.w);
    o1.x = f2bf((v1.x - m) * rstd * g1.x + b1.x);
    o1.y = f2bf((v1.y - m) * rstd * g1.y + b1.y);
    o1.z = f2bf((v1.z - m) * rstd * g1.z + b1.z);
    o1.w = f2bf((v1.w - m) * rstd * g1.w + b1.w);
    *reinterpret_cast<ushort4*>(&s_sn[r * 520 + lane * 4]) = o0;
    *reinterpret_cast<ushort4*>(&s_sn[r * 520 + 256 + lane * 4]) = o1;
    if (ct == 0) {
      ushort4 c0, c1;
      c0.x = f2bf(v0.x); c0.y = f2bf(v0.y); c0.z = f2bf(v0.z); c0.w = f2bf(v0.w);
      c1.x = f2bf(v1.x); c1.y = f2bf(v1.y); c1.z = f2bf(v1.z); c1.w = f2bf(v1.w);
      unsigned short* a2r = A2 + (size_t)(b_ * 16 + r) * 1024 + 512;
      *reinterpret_cast<ushort4*>(a2r + lane * 4) = c0;
      *reinterpret_cast<ushort4*>(a2r + 256 + lane * 4) = c1;
    }
  }

  const unsigned short* Bb = wpt + (size_t)(ct << 7) * 512;
  auto stage = [&](int buf, int k0) {
    #pragma unroll
    for (int i = 0; i < 4; ++i) {
      int ii = (w << 2) + i;
      GLD16(Bb + (size_t)((ii << 3) + sr8) * 512 + k0 + sc8, &sB[buf][ii * 512]);
    }
  };

  f32x4 acc[2];
  acc[0] = f32x4{0.f, 0.f, 0.f, 0.f};
  acc[1] = f32x4{0.f, 0.f, 0.f, 0.f};

  stage(0, 0);
  int cur = 0;
  for (int t = 0; t < 8; ++t) {
    __syncthreads();
    if (t + 1 < 8) stage(cur ^ 1, (t + 1) << 6);
    #pragma unroll
    for (int kk = 0; kk < 2; ++kk) {
      bf16x8 af = *reinterpret_cast<const bf16x8*>(&s_sn[lrow * 520 + (t << 6) + (kk << 5) + kt]);
      #pragma unroll
      for (int ni = 0; ni < 2; ++ni) {
        bf16x8 bfv = *reinterpret_cast<const bf16x8*>(
            &sB[cur][((w * 2 + ni) * 16 + lrow) * 64 + (kk << 5) + kt]);
        acc[ni] = __builtin_amdgcn_mfma_f32_16x16x32_bf16(af, bfv, acc[ni], 0, 0, 0);
      }
    }
    cur ^= 1;
  }

  const int rb = (lane >> 4) << 2;
  #pragma unroll
  for (int ni = 0; ni < 2; ++ni) {
    int col = (ct << 7) + (w * 2 + ni) * 16 + lrow;
    #pragma unroll
    for (int r = 0; r < 4; ++r) {
      int s = rb + r;
      q2[(size_t)((b_ << 4) + s) * 512 + col] = f2bf(acc[ni][r]);
    }
  }
}

// ---------------- logits[b][16][1024] = q2_b @ x_b^T  (bf16 out, BK=64) ----------------

__global__ __launch_bounds__(256) void logits_k(
    const unsigned short* __restrict__ q2, const unsigned short* __restrict__ x,
    unsigned short* __restrict__ out) {
  __shared__ unsigned short sA[2][1024];
  __shared__ unsigned short sB[2][8192];
  const int b = blockIdx.y, nt = blockIdx.x;
  const int lane = threadIdx.x & 63, w = threadIdx.x >> 6;
  const int lrow = lane & 15, kt = (lane >> 4) << 3;
  const int sr8 = lane >> 3, sc8 = (lane & 7) << 3;
  const unsigned short* Ab = q2 + ((size_t)b << 13);
  const unsigned short* Bb = x + (((size_t)(b << 10) + (nt << 7)) << 9);

  f32x4 acc[2];
  acc[0] = f32x4{0.f, 0.f, 0.f, 0.f};
  acc[1] = f32x4{0.f, 0.f, 0.f, 0.f};

  auto stage = [&](int buf, int k0) {
    #pragma unroll
    for (int i = 0; i < 4; ++i) {
      int ii = (w << 2) + i;
      GLD16(Bb + (size_t)((ii << 3) + sr8) * 512 + k0 + sc8, &sB[buf][ii * 512]);
    }
    if (w == 0) {
      #pragma unroll
      for (int i = 0; i < 2; ++i)
        GLD16(Ab + (size_t)((i << 3) + sr8) * 512 + k0 + sc8, &sA[buf][i * 512]);
    }
  };

  stage(0, 0);
  int cur = 0;
  for (int t = 0; t < 8; ++t) {
    __syncthreads();
    if (t + 1 < 8) stage(cur ^ 1, (t + 1) << 6);
    #pragma unroll
    for (int kk = 0; kk < 2; ++kk) {
      bf16x8 af = *reinterpret_cast<const bf16x8*>(&sA[cur][lrow * 64 + (kk << 5) + kt]);
      #pragma unroll
      for (int ni = 0; ni < 2; ++ni) {
        bf16x8 bfv = *reinterpret_cast<const bf16x8*>(
            &sB[cur][((w * 2 + ni) * 16 + lrow) * 64 + (kk << 5) + kt]);
        acc[ni] = __builtin_amdgcn_mfma_f32_16x16x32_bf16(af, bfv, acc[ni], 0, 0, 0);
      }
    }
    cur ^= 1;
  }

  const int rb = (lane >> 4) << 2;
  #pragma unroll
  for (int ni = 0; ni < 2; ++ni) {
    int n = (nt << 7) + (w * 2 + ni) * 16 + lrow;
    #pragma unroll
    for (int r = 0; r < 4; ++r) {
      int s = rb + r;
      out[(size_t)((b << 4) + s) * 1024 + n] = f2bf(acc[ni][r]);
    }
  }
}

// ---------------- pv_sm: softmax+colnorm (LDS attn) + ax MFMA vs xT (BK=64) ----------------

__global__ __launch_bounds__(256) void pv_sm_k(
    const unsigned short* __restrict__ logits, const unsigned short* __restrict__ xT,
    unsigned short* __restrict__ A2) {
  __shared__ float s_mi[16][2];
  __shared__ unsigned short s_at[16 * 1032];
  __shared__ unsigned short sA[2][8192];
  const int b_ = blockIdx.y, et = blockIdx.x;
  const int lane = threadIdx.x & 63, w = threadIdx.x >> 6;
  const int lrow = lane & 15, kt = (lane >> 4) << 3;
  const int sr8 = lane >> 3, sc8 = (lane & 7) << 3;
  const unsigned short* lg = logits + ((size_t)b_ << 14);

  #pragma unroll
  for (int rr = 0; rr < 4; ++rr) {
    int r = w * 4 + rr;
    const unsigned short* rp = lg + (size_t)r * 1024;
    float v[16];
    float mx = -3.4e38f;
    #pragma unroll
    for (int i = 0; i < 16; ++i) { v[i] = bf2f(rp[lane + (i << 6)]); mx = fmaxf(mx, v[i]); }
    #pragma unroll
    for (int o = 32; o > 0; o >>= 1) mx = fmaxf(mx, __shfl_xor(mx, o));
    float s = 0.f;
    #pragma unroll
    for (int i = 0; i < 16; ++i) s += __expf(v[i] - mx);
    #pragma unroll
    for (int o = 32; o > 0; o >>= 1) s += __shfl_xor(s, o);
    if (lane == 0) { s_mi[r][0] = mx; s_mi[r][1] = 1.0f / s; }
  }
  __syncthreads();

  #pragma unroll
  for (int j = 0; j < 4; ++j) {
    int c = threadIdx.x + (j << 8);
    float e[16];
    float cs = 0.f;
    #pragma unroll
    for (int s = 0; s < 16; ++s) {
      e[s] = __expf(bf2f(lg[(size_t)s * 1024 + c]) - s_mi[s][0]) * s_mi[s][1];
      cs += e[s];
    }
    float rv = 1.0f / (cs + 1e-8f);
    #pragma unroll
    for (int s = 0; s < 16; ++s) s_at[s * 1032 + c] = f2bf(e[s] * rv);
  }

  const unsigned short* Ab = xT + ((size_t)b_ << 19) + (size_t)(et << 7) * 1024;
  auto stage = [&](int buf, int k0) {
    #pragma unroll
    for (int i = 0; i < 4; ++i) {
      int ii = (w << 2) + i;
      GLD16(Ab + (size_t)((ii << 3) + sr8) * 1024 + k0 + sc8, &sA[buf][ii * 512]);
    }
  };

  f32x4 acc[2];
  acc[0] = f32x4{0.f, 0.f, 0.f, 0.f};
  acc[1] = f32x4{0.f, 0.f, 0.f, 0.f};

  stage(0, 0);
  int cur = 0;
  for (int t = 0; t < 16; ++t) {
    __syncthreads();
    if (t + 1 < 16) stage(cur ^ 1, (t + 1) << 6);
    #pragma unroll
    for (int kk = 0; kk < 2; ++kk) {
      bf16x8 bfv = *reinterpret_cast<const bf16x8*>(&s_at[lrow * 1032 + (t << 6) + (kk << 5) + kt]);
      #pragma unroll
      for (int mi = 0; mi < 2; ++mi) {
        bf16x8 af = *reinterpret_cast<const bf16x8*>(
            &sA[cur][((w * 2 + mi) * 16 + lrow) * 64 + (kk << 5) + kt]);
        acc[mi] = __builtin_amdgcn_mfma_f32_16x16x32_bf16(af, bfv, acc[mi], 0, 0, 0);
      }
    }
    cur ^= 1;
  }

  const int rb = (lane >> 4) << 2;
  const int s = lrow;
  #pragma unroll
  for (int mi = 0; mi < 2; ++mi) {
    int e0 = (et << 7) + (w * 2 + mi) * 16 + rb;
    ushort4 o;
    o.x = f2bf(acc[mi][0]); o.y = f2bf(acc[mi][1]);
    o.z = f2bf(acc[mi][2]); o.w = f2bf(acc[mi][3]);
    *reinterpret_cast<ushort4*>(&A2[(size_t)((b_ << 4) + s) * 1024 + e0]) = o;
  }
}

// ---------------- MFMA GEMM 64x64 (gates GEMM + wpt prep, BK=64) ----------------

template<int BIAS, int OUTBF16, int SCALE>
__global__ __launch_bounds__(256) void gemm_sm(
    const unsigned short* __restrict__ A, const unsigned short* __restrict__ W,
    const float* __restrict__ bias,
    void* __restrict__ Cout, int M, int N, int K, float scalev) {
  __shared__ unsigned short sA[2][4096];
  __shared__ unsigned short sB[2][4096];
  const int tid = threadIdx.x;
  const int lane = tid & 63, w = tid >> 6;

  int nwg = gridDim.x * gridDim.y;
  int flat = blockIdx.y * gridDim.x + blockIdx.x;
  if ((nwg & 7) == 0) { int c = nwg >> 3; flat = (flat & 7) * c + (flat >> 3); }
  const int row0 = (flat / gridDim.x) << 6;
  const int col0 = (flat % gridDim.x) << 6;

  const int lrow = lane & 15, kt = (lane >> 4) << 3;
  const int sr8 = lane >> 3, sc8 = (lane & 7) << 3;

  f32x4 acc[4];
  #pragma unroll
  for (int m = 0; m < 4; ++m) acc[m] = f32x4{0.f, 0.f, 0.f, 0.f};

  auto stage = [&](int buf, int k0) {
    #pragma unroll
    for (int i = 0; i < 2; ++i) {
      int ii = (w << 1) + i;
      int r = (ii << 3) + sr8;
      GLD16(A + (size_t)(row0 + r) * K + k0 + sc8, &sA[buf][ii * 512]);
      GLD16(W + (size_t)(col0 + r) * K + k0 + sc8, &sB[buf][ii * 512]);
    }
  };

  stage(0, 0);
  const int nt = K >> 6;
  int cur = 0;
  for (int t = 0; t < nt; ++t) {
    __syncthreads();
    if (t + 1 < nt) stage(cur ^ 1, (t + 1) << 6);
    #pragma unroll
    for (int kk = 0; kk < 2; ++kk) {
      bf16x8 bfv = *reinterpret_cast<const bf16x8*>(
          &sB[cur][((w << 4) + lrow) * 64 + (kk << 5) + kt]);
      #pragma unroll
      for (int m = 0; m < 4; ++m) {
        bf16x8 af = *reinterpret_cast<const bf16x8*>(
            &sA[cur][(m * 16 + lrow) * 64 + (kk << 5) + kt]);
        acc[m] = __builtin_amdgcn_mfma_f32_16x16x32_bf16(af, bfv, acc[m], 0, 0, 0);
      }
    }
    cur ^= 1;
  }

  const int rb = (lane >> 4) << 2;
  const int col = col0 + (w << 4) + lrow;
  float bv = BIAS ? bias[col] : 0.0f;
  #pragma unroll
  for (int m = 0; m < 4; ++m) {
    #pragma unroll
    for (int r = 0; r < 4; ++r) {
      int row = row0 + m * 16 + rb + r;
      float v = acc[m][r];
      if (SCALE) v *= scalev;
      v += bv;
      if (OUTBF16) ((unsigned short*)Cout)[(size_t)row * N + col] = f2bf(v);
      else ((float*)Cout)[(size_t)row * N + col] = v;
    }
  }
}

// ---------------- update_k: GRU + LN_mlp + mlp1 + mlp2 + LN_slots + q2 ----------------
// grid 64 (1 block per batch, 16 rows), 4 waves split 512 cols (128 each).
// B-operands (w1,w2,wpt) read from global to registers (L2-hot). A-operands in LDS.

template<int LAST>
__global__ __launch_bounds__(256) void update_k(
    const float* __restrict__ gates, float* __restrict__ slots,
    const float* __restrict__ g_m, const float* __restrict__ b_m,
    const float* __restrict__ b1v, const float* __restrict__ b2v,
    const unsigned short* __restrict__ w1, const unsigned short* __restrict__ w2,
    const float* __restrict__ g_s, const float* __restrict__ b_s,
    const unsigned short* __restrict__ wpt,
    unsigned short* __restrict__ q2, unsigned short* __restrict__ A2,
    float* __restrict__ out_final) {
  __shared__ float s_y[16][516];            // sgru f32, later slots_new f32
  __shared__ unsigned short s_lnm[16 * 536];
  __shared__ unsigned short s_h[16 * 536];
  __shared__ unsigned short s_sn[16 * 536];
  const int b = blockIdx.x;
  const int w = threadIdx.x >> 6, lane = threadIdx.x & 63;
  const int lrow = lane & 15, kt = (lane >> 4) << 3;
  const int rb = (lane >> 4) << 2;
  const int l8 = lane << 3;

  // ---- phase 1: GRU + LN_mlp (wave w -> rows 4w..4w+3) ----
  {
    const float* gg = g_m + l8;
    const float* bb = b_m + l8;
    #pragma unroll
    for (int rr = 0; rr < 4; ++rr) {
      int r = (w << 2) + rr;
      int row = (b << 4) + r;
      size_t gb = (size_t)row * 2048 + l8;
      size_t hb = (size_t)row * 512 + l8;
      float rs[8], zs[8], in_[8], hn[8], hv[8], y[8];
      #pragma unroll
      for (int c = 0; c < 2; ++c) {
        *reinterpret_cast<float4*>(rs + 4*c)  = *reinterpret_cast<const float4*>(gates + gb + 4*c);
        *reinterpret_cast<float4*>(zs + 4*c)  = *reinterpret_cast<const float4*>(gates + gb + 512 + 4*c);
        *reinterpret_cast<float4*>(in_ + 4*c) = *reinterpret_cast<const float4*>(gates + gb + 1024 + 4*c);
        *reinterpret_cast<float4*>(hn + 4*c)  = *reinterpret_cast<const float4*>(gates + gb + 1536 + 4*c);
        *reinterpret_cast<float4*>(hv + 4*c)  = *reinterpret_cast<const float4*>(slots + hb + 4*c);
      }
      float s = 0.f, q = 0.f;
      #pragma unroll
      for (int j = 0; j < 8; ++j) {
        float rg = 1.0f / (1.0f + expf(-rs[j]));
        float zg = 1.0f / (1.0f + expf(-zs[j]));
        float ng = tanhf(in_[j] + rg * hn[j]);
        float hh = (1.0f - zg) * ng + zg * hv[j];
        y[j] = hh; s += hh; q += hh * hh;
      }
      #pragma unroll
      for (int o = 32; o > 0; o >>= 1) { s += __shfl_xor(s, o); q += __shfl_xor(q, o); }
      float m = s * (1.0f / 512.0f);
      float rstd = rsqrtf(q * (1.0f / 512.0f) - m * m + 1e-8f);
      *reinterpret_cast<float4*>(&s_y[r][l8])     = *reinterpret_cast<float4*>(y);
      *reinterpret_cast<float4*>(&s_y[r][l8 + 4]) = *reinterpret_cast<float4*>(y + 4);
      unsigned int p[8];
      #pragma unroll
      for (int j = 0; j < 8; ++j) p[j] = f2bf((y[j] - m) * rstd * gg[j] + bb[j]);
      uint4 o4;
      o4.x = p[0] | (p[1] << 16); o4.y = p[2] | (p[3] << 16);
      o4.z = p[4] | (p[5] << 16); o4.w = p[6] | (p[7] << 16);
      *reinterpret_cast<uint4*>(&s_lnm[r * 536 + l8]) = o4;
    }
  }
  __syncthreads();

  // ---- phase 2: mlp1 h = relu(lnm @ w1^T + b1), cols w*128..+128 ----
  {
    f32x4 acc[8];
    #pragma unroll
    for (int ni = 0; ni < 8; ++ni) acc[ni] = f32x4{0.f, 0.f, 0.f, 0.f};
    for (int k0 = 0; k0 < 512; k0 += 32) {
      bf16x8 af = *reinterpret_cast<const bf16x8*>(&s_lnm[lrow * 536 + k0 + kt]);
      #pragma unroll
      for (int ni = 0; ni < 8; ++ni) {
        int c = (w << 7) + (ni << 4) + lrow;
        bf16x8 bfv = *reinterpret_cast<const bf16x8*>(w1 + (size_t)c * 512 + k0 + kt);
        acc[ni] = __builtin_amdgcn_mfma_f32_16x16x32_bf16(af, bfv, acc[ni], 0, 0, 0);
      }
    }
    #pragma unroll
    for (int ni = 0; ni < 8; ++ni) {
      int c = (w << 7) + (ni << 4) + lrow;
      float bv = b1v[c];
      #pragma unroll
      for (int r4 = 0; r4 < 4; ++r4)
        s_h[(rb + r4) * 536 + c] = f2bf(fmaxf(acc[ni][r4] + bv, 0.0f));
    }
  }
  __syncthreads();

  // ---- phase 3: mlp2 out = h @ w2^T + b2 + sgru -> s_y (overwrite) ----
  {
    f32x4 acc[8];
    #pragma unroll
    for (int ni = 0; ni < 8; ++ni) acc[ni] = f32x4{0.f, 0.f, 0.f, 0.f};
    for (int k0 = 0; k0 < 512; k0 += 32) {
      bf16x8 af = *reinterpret_cast<const bf16x8*>(&s_h[lrow * 536 + k0 + kt]);
      #pragma unroll
      for (int ni = 0; ni < 8; ++ni) {
        int c = (w << 7) + (ni << 4) + lrow;
        bf16x8 bfv = *reinterpret_cast<const bf16x8*>(w2 + (size_t)c * 512 + k0 + kt);
        acc[ni] = __builtin_amdgcn_mfma_f32_16x16x32_bf16(af, bfv, acc[ni], 0, 0, 0);
      }
    }
    #pragma unroll
    for (int ni = 0; ni < 8; ++ni) {
      int c = (w << 7) + (ni << 4) + lrow;
      float bv = b2v[c];
      #pragma unroll
      for (int r4 = 0; r4 < 4; ++r4)
        s_y[rb + r4][c] = acc[ni][r4] + bv + s_y[rb + r4][c];
    }
  }
  __syncthreads();

  // ---- phase 4: write slots_new (or d_out), LN_slots -> s_sn + A2 raw ----
  {
    const float* gg = g_s + l8;
    const float* bb = b_s + l8;
    float* outp = LAST ? out_final : slots;
    #pragma unroll
    for (int rr = 0; rr < 4; ++rr) {
      int r = (w << 2) + rr;
      int row = (b << 4) + r;
      float v[8];
      *reinterpret_cast<float4*>(v)     = *reinterpret_cast<const float4*>(&s_y[r][l8]);
      *reinterpret_cast<float4*>(v + 4) = *reinterpret_cast<const float4*>(&s_y[r][l8 + 4]);
      *reinterpret_cast<float4*>(outp + (size_t)row * 512 + l8)     = *reinterpret_cast<float4*>(v);
      *reinterpret_cast<float4*>(outp + (size_t)row * 512 + l8 + 4) = *reinterpret_cast<float4*>(v + 4);
      if (!LAST) {
        float s = 0.f, q = 0.f;
        #pragma unroll
        for (int j = 0; j < 8; ++j) { s += v[j]; q += v[j] * v[j]; }
        #pragma unroll
        for (int o = 32; o > 0; o >>= 1) { s += __shfl_xor(s, o); q += __shfl_xor(q, o); }
        float m = s * (1.0f / 512.0f);
        float rstd = rsqrtf(q * (1.0f / 512.0f) - m * m + 1e-8f);
        unsigned int p[8], c[8];
        #pragma unroll
        for (int j = 0; j < 8; ++j) {
          p[j] = f2bf((v[j] - m) * rstd * gg[j] + bb[j]);
          c[j] = f2bf(v[j]);
        }
        uint4 o4, c4;
        o4.x = p[0] | (p[1] << 16); o4.y = p[2] | (p[3] << 16);
        o4.z = p[4] | (p[5] << 16); o4.w = p[6] | (p[7] << 16);
        c4.x = c[0] | (c[1] << 16); c4.y = c[2] | (c[3] << 16);
        c4.z = c[4] | (c[5] << 16); c4.w = c[6] | (c[7] << 16);
        *reinterpret_cast<uint4*>(&s_sn[r * 536 + l8]) = o4;
        *reinterpret_cast<uint4*>(A2 + (size_t)row * 1024 + 512 + l8) = c4;
      }
    }
  }
  if (LAST) return;
  __syncthreads();

  // ---- phase 5: q2 = sn @ W' (wpt rows = q2 cols) ----
  {
    f32x4 acc[8];
    #pragma unroll
    for (int ni = 0; ni < 8; ++ni) acc[ni] = f32x4{0.f, 0.f, 0.f, 0.f};
    for (int k0 = 0; k0 < 512; k0 += 32) {
      bf16x8 af = *reinterpret_cast<const bf16x8*>(&s_sn[lrow * 536 + k0 + kt]);
      #pragma unroll
      for (int ni = 0; ni < 8; ++ni) {
        int c = (w << 7) + (ni << 4) + lrow;
        bf16x8 bfv = *reinterpret_cast<const bf16x8*>(wpt + (size_t)c * 512 + k0 + kt);
        acc[ni] = __builtin_amdgcn_mfma_f32_16x16x32_bf16(af, bfv, acc[ni], 0, 0, 0);
      }
    }
    #pragma unroll
    for (int ni = 0; ni < 8; ++ni) {
      int c = (w << 7) + (ni << 4) + lrow;
      #pragma unroll
      for (int r4 = 0; r4 < 4; ++r4)
        q2[(size_t)((b << 4) + rb + r4) * 512 + c] = f2bf(acc[ni][r4]);
    }
  }
}

// ---------------- host launch ----------------

extern "C" void kernel_launch(void* const* d_in, const int* in_sizes, int n_in,
                              void* d_out, int out_size, void* d_ws, size_t ws_size,
                              hipStream_t stream) {
  const float* inputs  = (const float*)d_in[0];
  const float* noise   = (const float*)d_in[1];
  const float* slot_mu = (const float*)d_in[2];
  const float* slot_ls = (const float*)d_in[3];
  const float* ln_in_g = (const float*)d_in[4];
  const float* ln_in_b = (const float*)d_in[5];
  const float* ln_s_g  = (const float*)d_in[6];
  const float* ln_s_b  = (const float*)d_in[7];
  const float* ln_m_g  = (const float*)d_in[8];
  const float* ln_m_b  = (const float*)d_in[9];
  const float* Wq   = (const float*)d_in[10];
  const float* Wk   = (const float*)d_in[11];
  const float* Wv   = (const float*)d_in[12];
  const float* w_ih = (const float*)d_in[13];
  const float* w_hh = (const float*)d_in[14];
  const float* b_ih = (const float*)d_in[15];
  const float* b_hh = (const float*)d_in[16];
  const float* w1   = (const float*)d_in[17];
  const float* b1   = (const float*)d_in[18];
  const float* w2   = (const float*)d_in[19];
  const float* b2   = (const float*)d_in[20];

  const int BN = 65536, BS = 1024;

  uintptr_t base = (uintptr_t)d_ws;
  auto alloc = [&](size_t bytes) {
    void* p = (void*)base;
    base += (bytes + 255) & ~(size_t)255;
    return p;
  };
  unsigned short* x_bf    = (unsigned short*)alloc((size_t)BN * 512 * 2);
  unsigned short* xT      = (unsigned short*)alloc((size_t)64 * 512 * 1024 * 2);
  unsigned short* wqT     = (unsigned short*)alloc(512 * 512 * 2);
  unsigned short* wkT     = (unsigned short*)alloc(512 * 512 * 2);
  unsigned short* wvT     = (unsigned short*)alloc(512 * 512 * 2);
  unsigned short* wpt     = (unsigned short*)alloc(512 * 512 * 2);
  unsigned short* wih_bf  = (unsigned short*)alloc((size_t)1536 * 512 * 2);
  unsigned short* wcat_bf = (unsigned short*)alloc((size_t)2048 * 1024 * 2);
  float*          bcat    = (float*)alloc(2048 * 4);
  unsigned short* w1_bf   = (unsigned short*)alloc(512 * 512 * 2);
  unsigned short* w2_bf   = (unsigned short*)alloc(512 * 512 * 2);
  float*          slots   = (float*)alloc((size_t)BS * 512 * 4);
  unsigned short* A2      = (unsigned short*)alloc((size_t)BS * 1024 * 2);
  unsigned short* q2_bf   = (unsigned short*)alloc((size_t)BS * 512 * 2);
  unsigned short* logits  = (unsigned short*)alloc((size_t)64 * 16 * 1024 * 2);
  float*          gates   = (float*)alloc((size_t)BS * 2048 * 4);
  (void)ws_size; (void)n_in; (void)in_sizes; (void)out_size;

  const float scale = 0.044194173824159216f;  // 512^-0.5

  // prologue (6 dispatches)
  wprep_k<<<12296, 256, 0, stream>>>(w1, w2, w_ih, w_hh, b_ih, b_hh,
                                     slot_mu, slot_ls, noise,
                                     w1_bf, w2_bf, wih_bf, wcat_bf, bcat, slots);
  tcast3_k<<<dim3(16, 16, 3), 256, 0, stream>>>(Wq, Wk, Wv, wqT, wkT, wvT);
  gemm_sm<0,1,1><<<dim3(8, 8), 256, 0, stream>>>(
      wkT, wqT, nullptr, wpt, 512, 512, 512, scale);
  gemm_cat<<<dim3(4, 12), 256, 0, stream>>>(
      wih_bf, wvT, wcat_bf, 1536, 512, 512, 1024);
  ln_rows_k<<<16384, 256, 0, stream>>>(inputs, ln_in_g, ln_in_b, x_bf, BN);
  xt_k<<<dim3(16, 8, 64), 256, 0, stream>>>(x_bf, xT);

  // pre-loop seed: sn/q2/A2-right from initial slots
  q2ln_k<<<dim3(4, 64), 256, 0, stream>>>(slots, ln_s_g, ln_s_b, wpt, q2_bf, A2);

  for (int it = 0; it < 3; ++it) {
    logits_k<<<dim3(8, 64), 256, 0, stream>>>(q2_bf, x_bf, logits);
    pv_sm_k<<<dim3(4, 64), 256, 0, stream>>>(logits, xT, A2);
    gemm_sm<1,0,0><<<dim3(32, 16), 256, 0, stream>>>(
        A2, wcat_bf, bcat, gates, BS, 2048, 1024, 1.0f);
    if (it < 2)
      update_k<0><<<64, 256, 0, stream>>>(gates, slots, ln_m_g, ln_m_b, b1, b2,
                                          w1_bf, w2_bf, ln_s_g, ln_s_b, wpt,
                                          q2_bf, A2, (float*)d_out);
    else
      update_k<1><<<64, 256, 0, stream>>>(gates, slots, ln_m_g, ln_m_b, b1, b2,
                                          w1_bf, w2_bf, ln_s_g, ln_s_b, wpt,
                                          q2_bf, A2, (float*)d_out);
  }
}

// Round 12
// 322.450 us; speedup vs baseline: 1.2498x; 1.2498x over previous
//
#include <hip/hip_runtime.h>
#include <hip/hip_bf16.h>
#include <cstdint>
#include <cstddef>

// Shapes fixed: B=64, N=1024, D=512, S=16, 3 iterations.
// Algebra: logits = sn·W'·x^T, W' = scale·Wq^T·Wk   (k never materialized)
//          ax = attn·x;  upd@Wih^T = ax@(Wih·Wv)^T  (v never materialized)
// R12: R10 structure (all stages >=256 blocks) + softmax row-stats fused
//      into logits_k epilogue (pv_sm phase1 reads 8 partials, not 33MB).

typedef __bf16 bf16x8 __attribute__((ext_vector_type(8)));
typedef float f32x4 __attribute__((ext_vector_type(4)));

__device__ __forceinline__ float bf2f(unsigned int u) {
  union { unsigned int i; float f; } v; v.i = u << 16; return v.f;
}
__device__ __forceinline__ unsigned short f2bf(float x) {
  __hip_bfloat16 h = __float2bfloat16(x);
  unsigned short u;
  __builtin_memcpy(&u, &h, 2);
  return u;
}

#define GLD16(gp, lp)                                                       \
  __builtin_amdgcn_global_load_lds(                                         \
      (const __attribute__((address_space(1))) void*)(gp),                  \
      (__attribute__((address_space(3))) void*)(lp), 16, 0, 0)

// ---------------- merged prep (segmented grid) ----------------

__global__ void wprep_k(const float* __restrict__ w1, const float* __restrict__ w2,
                        const float* __restrict__ wih, const float* __restrict__ whh,
                        const float* __restrict__ bih, const float* __restrict__ bhh,
                        const float* __restrict__ mu, const float* __restrict__ ls,
                        const float* __restrict__ noise,
                        unsigned short* __restrict__ w1_bf, unsigned short* __restrict__ w2_bf,
                        unsigned short* __restrict__ wih_bf, unsigned short* __restrict__ wcat,
                        float* __restrict__ bcat, float* __restrict__ slots) {
  int blk = blockIdx.x, t = threadIdx.x;
  if (blk < 1024) {
    int i = blk * 256 + t; w1_bf[i] = f2bf(w1[i]);
  } else if (blk < 2048) {
    int i = (blk - 1024) * 256 + t; w2_bf[i] = f2bf(w2[i]);
  } else if (blk < 5120) {
    int i = (blk - 2048) * 256 + t; wih_bf[i] = f2bf(wih[i]);
  } else if (blk < 7168) {
    int i = (blk - 5120) * 256 + t;  // rows 0..1024 right half
    int j = i >> 9, d = i & 511;
    wcat[(size_t)j * 1024 + 512 + d] = f2bf(whh[(size_t)j * 512 + d]);
  } else if (blk < 8192) {
    int i = (blk - 7168) * 256 + t;  // rows 1536..2048 right half
    int j = i >> 9, d = i & 511;
    wcat[(size_t)(1536 + j) * 1024 + 512 + d] = f2bf(whh[(size_t)(1024 + j) * 512 + d]);
  } else if (blk < 10240) {
    int i = (blk - 8192) * 256 + t;  // zeros
    if (i < 262144) {
      int j = i >> 9, d = i & 511;
      wcat[(size_t)(1536 + j) * 1024 + d] = 0;
    } else {
      int k = i - 262144;
      int j = k >> 9, d = k & 511;
      wcat[(size_t)(1024 + j) * 1024 + 512 + d] = 0;
    }
  } else if (blk < 10248) {
    int j = (blk - 10240) * 256 + t;  // 2048
    float v;
    if (j < 1024)      v = bih[j] + bhh[j];
    else if (j < 1536) v = bih[j];
    else               v = bhh[j - 512];
    bcat[j] = v;
  } else {
    int i = (blk - 10248) * 256 + t;  // 524288
    int d = i & 511;
    slots[i] = mu[d] + expf(ls[d]) * noise[i];
  }
}

// transpose + cast Wq, Wk, Wv: grid (16,16,3)
__global__ __launch_bounds__(256) void tcast3_k(const float* __restrict__ Wq,
                                                const float* __restrict__ Wk,
                                                const float* __restrict__ Wv,
                                                unsigned short* __restrict__ wqT,
                                                unsigned short* __restrict__ wkT,
                                                unsigned short* __restrict__ wvT) {
  __shared__ float tt[32][33];
  const float* in = blockIdx.z == 0 ? Wq : (blockIdx.z == 1 ? Wk : Wv);
  unsigned short* out = blockIdx.z == 0 ? wqT : (blockIdx.z == 1 ? wkT : wvT);
  int c0 = blockIdx.x << 5, r0 = blockIdx.y << 5;
  int tx = threadIdx.x & 31, ty = threadIdx.x >> 5;
  #pragma unroll
  for (int i = 0; i < 4; ++i)
    tt[ty + 8 * i][tx] = in[(size_t)(r0 + ty + 8 * i) * 512 + c0 + tx];
  __syncthreads();
  #pragma unroll
  for (int i = 0; i < 4; ++i)
    out[(size_t)(c0 + ty + 8 * i) * 512 + r0 + tx] = f2bf(tt[tx][ty + 8 * i]);
}

// ---------------- layernorm inputs (wave per row, D=512) ----------------

__global__ __launch_bounds__(256) void ln_rows_k(
    const float* __restrict__ in, const float* __restrict__ g, const float* __restrict__ b,
    unsigned short* __restrict__ out, int rows) {
  int w = threadIdx.x >> 6, lane = threadIdx.x & 63;
  int row = (blockIdx.x << 2) + w;
  if (row >= rows) return;
  const float4* rp = reinterpret_cast<const float4*>(in + (size_t)row * 512);
  float4 v0 = rp[lane], v1 = rp[lane + 64];
  float s = v0.x + v0.y + v0.z + v0.w + v1.x + v1.y + v1.z + v1.w;
  float q = v0.x*v0.x + v0.y*v0.y + v0.z*v0.z + v0.w*v0.w
          + v1.x*v1.x + v1.y*v1.y + v1.z*v1.z + v1.w*v1.w;
  #pragma unroll
  for (int o = 32; o > 0; o >>= 1) { s += __shfl_xor(s, o); q += __shfl_xor(q, o); }
  float m = s * (1.0f / 512.0f);
  float rstd = rsqrtf(q * (1.0f / 512.0f) - m * m + 1e-8f);
  const float4* gp = reinterpret_cast<const float4*>(g);
  const float4* bp = reinterpret_cast<const float4*>(b);
  float4 g0 = gp[lane], g1 = gp[lane + 64];
  float4 b0 = bp[lane], b1 = bp[lane + 64];
  ushort4 o0, o1;
  o0.x = f2bf((v0.x - m) * rstd * g0.x + b0.x);
  o0.y = f2bf((v0.y - m) * rstd * g0.y + b0.y);
  o0.z = f2bf((v0.z - m) * rstd * g0.z + b0.z);
  o0.w = f2bf((v0.w - m) * rstd * g0.w + b0.w);
  o1.x = f2bf((v1.x - m) * rstd * g1.x + b1.x);
  o1.y = f2bf((v1.y - m) * rstd * g1.y + b1.y);
  o1.z = f2bf((v1.z - m) * rstd * g1.z + b1.z);
  o1.w = f2bf((v1.w - m) * rstd * g1.w + b1.w);
  ushort4* op = reinterpret_cast<ushort4*>(out + (size_t)row * 512);
  op[lane] = o0; op[lane + 64] = o1;
}

// ---------------- xT[b][e][n] = x_bf[b*1024+n][e] ----------------

__global__ __launch_bounds__(256) void xt_k(const unsigned short* __restrict__ x,
                                            unsigned short* __restrict__ xT) {
  __shared__ unsigned short t[64][68];
  int nt = blockIdx.x, et = blockIdx.y, b = blockIdx.z;
  int r = threadIdx.x >> 3, c8 = (threadIdx.x & 7) << 3;
  #pragma unroll
  for (int p = 0; p < 2; ++p) {
    int row = r + (p << 5);
    *reinterpret_cast<uint4*>(&t[row][c8]) = *reinterpret_cast<const uint4*>(
        x + ((size_t)(b << 10) + (nt << 6) + row) * 512 + (et << 6) + c8);
  }
  __syncthreads();
  #pragma unroll
  for (int p = 0; p < 2; ++p) {
    int erow = r + (p << 5);
    ushort4 a, bb;
    #pragma unroll
    for (int j = 0; j < 4; ++j) ((unsigned short*)&a)[j] = t[c8 + j][erow];
    #pragma unroll
    for (int j = 0; j < 4; ++j) ((unsigned short*)&bb)[j] = t[c8 + 4 + j][erow];
    unsigned short* o = xT + ((size_t)(b << 9) + (et << 6) + erow) * 1024 + (nt << 6) + c8;
    *reinterpret_cast<ushort4*>(o) = a;
    *reinterpret_cast<ushort4*>(o + 4) = bb;
  }
}

// GRU (fused-gates layout) + LN
__global__ __launch_bounds__(256) void gru_ln_k(
    const float* __restrict__ gates, const float* __restrict__ hp,
    const float* __restrict__ g, const float* __restrict__ b,
    float* __restrict__ sgru, unsigned short* __restrict__ lnm) {
  int w = threadIdx.x >> 6, lane = threadIdx.x & 63;
  int row = (blockIdx.x << 2) + w;
  size_t gb = (size_t)row * 2048 + (lane << 3);
  size_t hb = (size_t)row * 512 + (lane << 3);
  float rs[8], zs[8], in_[8], hn[8], hv[8], y[8];
  #pragma unroll
  for (int c = 0; c < 2; ++c) {
    *reinterpret_cast<float4*>(rs + 4*c)  = *reinterpret_cast<const float4*>(gates + gb + 4*c);
    *reinterpret_cast<float4*>(zs + 4*c)  = *reinterpret_cast<const float4*>(gates + gb + 512 + 4*c);
    *reinterpret_cast<float4*>(in_ + 4*c) = *reinterpret_cast<const float4*>(gates + gb + 1024 + 4*c);
    *reinterpret_cast<float4*>(hn + 4*c)  = *reinterpret_cast<const float4*>(gates + gb + 1536 + 4*c);
    *reinterpret_cast<float4*>(hv + 4*c)  = *reinterpret_cast<const float4*>(hp + hb + 4*c);
  }
  float s = 0.f, q = 0.f;
  #pragma unroll
  for (int j = 0; j < 8; ++j) {
    float r = 1.0f / (1.0f + expf(-rs[j]));
    float z = 1.0f / (1.0f + expf(-zs[j]));
    float n = tanhf(in_[j] + r * hn[j]);
    float h = (1.0f - z) * n + z * hv[j];
    y[j] = h; s += h; q += h * h;
  }
  #pragma unroll
  for (int o = 32; o > 0; o >>= 1) { s += __shfl_xor(s, o); q += __shfl_xor(q, o); }
  float m = s * (1.0f / 512.0f);
  float rstd = rsqrtf(q * (1.0f / 512.0f) - m * m + 1e-8f);
  const float* gg = g + (lane << 3);
  const float* bb = b + (lane << 3);
  #pragma unroll
  for (int c = 0; c < 2; ++c)
    *reinterpret_cast<float4*>(sgru + hb + 4*c) = *reinterpret_cast<const float4*>(y + 4*c);
  uint4 o4;
  unsigned int p[8];
  #pragma unroll
  for (int j = 0; j < 8; ++j) p[j] = f2bf((y[j] - m) * rstd * gg[j] + bb[j]);
  o4.x = p[0] | (p[1] << 16); o4.y = p[2] | (p[3] << 16);
  o4.z = p[4] | (p[5] << 16); o4.w = p[6] | (p[7] << 16);
  *reinterpret_cast<uint4*>(lnm + hb) = o4;
}

// ---------------- gemm_cat: wcat[j][0..512) = bf16(wih @ Wv), ldc=1024, BK=64 ----------------

__global__ __launch_bounds__(256) void gemm_cat(
    const unsigned short* __restrict__ A, const unsigned short* __restrict__ W,
    unsigned short* __restrict__ Cout, int M, int N, int K, int ldc) {
  __shared__ unsigned short sA[2][8192];
  __shared__ unsigned short sB[2][8192];
  const int tid = threadIdx.x;
  const int lane = tid & 63, w = tid >> 6;

  int nwg = gridDim.x * gridDim.y;
  int flat = blockIdx.y * gridDim.x + blockIdx.x;
  if ((nwg & 7) == 0) { int c = nwg >> 3; flat = (flat & 7) * c + (flat >> 3); }
  const int row0 = (flat / gridDim.x) << 7;
  const int col0 = (flat % gridDim.x) << 7;

  const int wm = (w >> 1) << 6, wn = (w & 1) << 6;
  const int lrow = lane & 15, kt = (lane >> 4) << 3;
  const int sr8 = lane >> 3, sc8 = (lane & 7) << 3;

  f32x4 acc[4][4];
  #pragma unroll
  for (int m = 0; m < 4; ++m)
    #pragma unroll
    for (int n = 0; n < 4; ++n) acc[m][n] = f32x4{0.f, 0.f, 0.f, 0.f};

  auto stage = [&](int buf, int k0) {
    #pragma unroll
    for (int i = 0; i < 4; ++i) {
      int ii = (w << 2) + i;
      int r = (ii << 3) + sr8;
      GLD16(A + (size_t)(row0 + r) * K + k0 + sc8, &sA[buf][ii * 512]);
      GLD16(W + (size_t)(col0 + r) * K + k0 + sc8, &sB[buf][ii * 512]);
    }
  };

  stage(0, 0);
  const int nt = K >> 6;
  int cur = 0;
  for (int t = 0; t < nt; ++t) {
    __syncthreads();
    if (t + 1 < nt) stage(cur ^ 1, (t + 1) << 6);
    #pragma unroll
    for (int kk = 0; kk < 2; ++kk) {
      bf16x8 af[4], bfv[4];
      #pragma unroll
      for (int m = 0; m < 4; ++m)
        af[m] = *reinterpret_cast<const bf16x8*>(&sA[cur][(wm + m * 16 + lrow) * 64 + (kk << 5) + kt]);
      #pragma unroll
      for (int n = 0; n < 4; ++n)
        bfv[n] = *reinterpret_cast<const bf16x8*>(&sB[cur][(wn + n * 16 + lrow) * 64 + (kk << 5) + kt]);
      #pragma unroll
      for (int m = 0; m < 4; ++m)
        #pragma unroll
        for (int n = 0; n < 4; ++n)
          acc[m][n] = __builtin_amdgcn_mfma_f32_16x16x32_bf16(af[m], bfv[n], acc[m][n], 0, 0, 0);
    }
    cur ^= 1;
  }

  const int rb = (lane >> 4) << 2;
  #pragma unroll
  for (int m = 0; m < 4; ++m) {
    #pragma unroll
    for (int n = 0; n < 4; ++n) {
      int col = col0 + wn + n * 16 + lrow;
      #pragma unroll
      for (int r = 0; r < 4; ++r) {
        int row = row0 + wm + m * 16 + rb + r;
        Cout[(size_t)row * ldc + col] = f2bf(acc[m][n][r]);
      }
    }
  }
}

// ---------------- q2ln: LN(slots_b) in LDS, then q2 = sn @ W' tile (BK=64) ----------------

__global__ __launch_bounds__(256) void q2ln_k(
    const float* __restrict__ slots, const float* __restrict__ g, const float* __restrict__ b,
    const unsigned short* __restrict__ wpt, unsigned short* __restrict__ q2,
    unsigned short* __restrict__ A2) {
  __shared__ unsigned short s_sn[16 * 520];
  __shared__ unsigned short sB[2][8192];
  const int b_ = blockIdx.y, ct = blockIdx.x;
  const int lane = threadIdx.x & 63, w = threadIdx.x >> 6;
  const int lrow = lane & 15, kt = (lane >> 4) << 3;
  const int sr8 = lane >> 3, sc8 = (lane & 7) << 3;

  const float4* gp = reinterpret_cast<const float4*>(g);
  const float4* bp = reinterpret_cast<const float4*>(b);
  float4 g0 = gp[lane], g1 = gp[lane + 64];
  float4 b0 = bp[lane], b1 = bp[lane + 64];
  #pragma unroll
  for (int rr = 0; rr < 4; ++rr) {
    int r = w * 4 + rr;
    const float4* rp = reinterpret_cast<const float4*>(slots + (size_t)(b_ * 16 + r) * 512);
    float4 v0 = rp[lane], v1 = rp[lane + 64];
    float s = v0.x + v0.y + v0.z + v0.w + v1.x + v1.y + v1.z + v1.w;
    float q = v0.x*v0.x + v0.y*v0.y + v0.z*v0.z + v0.w*v0.w
            + v1.x*v1.x + v1.y*v1.y + v1.z*v1.z + v1.w*v1.w;
    #pragma unroll
    for (int o = 32; o > 0; o >>= 1) { s += __shfl_xor(s, o); q += __shfl_xor(q, o); }
    float m = s * (1.0f / 512.0f);
    float rstd = rsqrtf(q * (1.0f / 512.0f) - m * m + 1e-8f);
    ushort4 o0, o1;
    o0.x = f2bf((v0.x - m) * rstd * g0.x + b0.x);
    o0.y = f2bf((v0.y - m) * rstd * g0.y + b0.y);
    o0.z = f2bf((v0.z - m) * rstd * g0.z + b0.z);
    o0.w = f2bf((v0.w - m) * rstd * g0.w + b0.w);
    o1.x = f2bf((v1.x - m) * rstd * g1.x + b1.x);
    o1.y = f2bf((v1.y - m) * rstd * g1.y + b1.y);
    o1.z = f2bf((v1.z - m) * rstd * g1.z + b1.z);
    o1.w = f2bf((v1.w - m) * rstd * g1.w + b1.w);
    *reinterpret_cast<ushort4*>(&s_sn[r * 520 + lane * 4]) = o0;
    *reinterpret_cast<ushort4*>(&s_sn[r * 520 + 256 + lane * 4]) = o1;
    if (ct == 0) {
      ushort4 c0, c1;
      c0.x = f2bf(v0.x); c0.y = f2bf(v0.y); c0.z = f2bf(v0.z); c0.w = f2bf(v0.w);
      c1.x = f2bf(v1.x); c1.y = f2bf(v1.y); c1.z = f2bf(v1.z); c1.w = f2bf(v1.w);
      unsigned short* a2r = A2 + (size_t)(b_ * 16 + r) * 1024 + 512;
      *reinterpret_cast<ushort4*>(a2r + lane * 4) = c0;
      *reinterpret_cast<ushort4*>(a2r + 256 + lane * 4) = c1;
    }
  }

  const unsigned short* Bb = wpt + (size_t)(ct << 7) * 512;
  auto stage = [&](int buf, int k0) {
    #pragma unroll
    for (int i = 0; i < 4; ++i) {
      int ii = (w << 2) + i;
      GLD16(Bb + (size_t)((ii << 3) + sr8) * 512 + k0 + sc8, &sB[buf][ii * 512]);
    }
  };

  f32x4 acc[2];
  acc[0] = f32x4{0.f, 0.f, 0.f, 0.f};
  acc[1] = f32x4{0.f, 0.f, 0.f, 0.f};

  stage(0, 0);
  int cur = 0;
  for (int t = 0; t < 8; ++t) {
    __syncthreads();
    if (t + 1 < 8) stage(cur ^ 1, (t + 1) << 6);
    #pragma unroll
    for (int kk = 0; kk < 2; ++kk) {
      bf16x8 af = *reinterpret_cast<const bf16x8*>(&s_sn[lrow * 520 + (t << 6) + (kk << 5) + kt]);
      #pragma unroll
      for (int ni = 0; ni < 2; ++ni) {
        bf16x8 bfv = *reinterpret_cast<const bf16x8*>(
            &sB[cur][((w * 2 + ni) * 16 + lrow) * 64 + (kk << 5) + kt]);
        acc[ni] = __builtin_amdgcn_mfma_f32_16x16x32_bf16(af, bfv, acc[ni], 0, 0, 0);
      }
    }
    cur ^= 1;
  }

  const int rb = (lane >> 4) << 2;
  #pragma unroll
  for (int ni = 0; ni < 2; ++ni) {
    int col = (ct << 7) + (w * 2 + ni) * 16 + lrow;
    #pragma unroll
    for (int r = 0; r < 4; ++r) {
      int s = rb + r;
      q2[(size_t)((b_ << 4) + s) * 512 + col] = f2bf(acc[ni][r]);
    }
  }
}

// ---------------- logits + per-chunk softmax stats (bf16 out, BK=64) ----------------
// lstats[b][s][nt][2] = (max, sumexp) over this block's 128-n chunk.

__global__ __launch_bounds__(256) void logits_k(
    const unsigned short* __restrict__ q2, const unsigned short* __restrict__ x,
    unsigned short* __restrict__ out, float* __restrict__ lstats) {
  __shared__ unsigned short sA[2][1024];
  __shared__ unsigned short sB[2][8192];
  __shared__ float sstat[16][4][2];
  const int b = blockIdx.y, nt = blockIdx.x;
  const int lane = threadIdx.x & 63, w = threadIdx.x >> 6;
  const int lrow = lane & 15, kt = (lane >> 4) << 3;
  const int sr8 = lane >> 3, sc8 = (lane & 7) << 3;
  const unsigned short* Ab = q2 + ((size_t)b << 13);
  const unsigned short* Bb = x + (((size_t)(b << 10) + (nt << 7)) << 9);

  f32x4 acc[2];
  acc[0] = f32x4{0.f, 0.f, 0.f, 0.f};
  acc[1] = f32x4{0.f, 0.f, 0.f, 0.f};

  auto stage = [&](int buf, int k0) {
    #pragma unroll
    for (int i = 0; i < 4; ++i) {
      int ii = (w << 2) + i;
      GLD16(Bb + (size_t)((ii << 3) + sr8) * 512 + k0 + sc8, &sB[buf][ii * 512]);
    }
    if (w == 0) {
      #pragma unroll
      for (int i = 0; i < 2; ++i)
        GLD16(Ab + (size_t)((i << 3) + sr8) * 512 + k0 + sc8, &sA[buf][i * 512]);
    }
  };

  stage(0, 0);
  int cur = 0;
  for (int t = 0; t < 8; ++t) {
    __syncthreads();
    if (t + 1 < 8) stage(cur ^ 1, (t + 1) << 6);
    #pragma unroll
    for (int kk = 0; kk < 2; ++kk) {
      bf16x8 af = *reinterpret_cast<const bf16x8*>(&sA[cur][lrow * 64 + (kk << 5) + kt]);
      #pragma unroll
      for (int ni = 0; ni < 2; ++ni) {
        bf16x8 bfv = *reinterpret_cast<const bf16x8*>(
            &sB[cur][((w * 2 + ni) * 16 + lrow) * 64 + (kk << 5) + kt]);
        acc[ni] = __builtin_amdgcn_mfma_f32_16x16x32_bf16(af, bfv, acc[ni], 0, 0, 0);
      }
    }
    cur ^= 1;
  }

  const int rb = (lane >> 4) << 2;
  unsigned short lv[2][4];
  #pragma unroll
  for (int ni = 0; ni < 2; ++ni) {
    int n = (nt << 7) + (w * 2 + ni) * 16 + lrow;
    #pragma unroll
    for (int r = 0; r < 4; ++r) {
      unsigned short u = f2bf(acc[ni][r]);
      lv[ni][r] = u;
      out[(size_t)((b << 4) + rb + r) * 1024 + n] = u;
    }
  }
  // per-chunk stats over the bf16-rounded values (matches pv phase-2 inputs)
  #pragma unroll
  for (int r = 0; r < 4; ++r) {
    float v0 = bf2f(lv[0][r]), v1 = bf2f(lv[1][r]);
    float m = fmaxf(v0, v1);
    #pragma unroll
    for (int o = 1; o < 16; o <<= 1) m = fmaxf(m, __shfl_xor(m, o));
    float l = __expf(v0 - m) + __expf(v1 - m);
    #pragma unroll
    for (int o = 1; o < 16; o <<= 1) l += __shfl_xor(l, o);
    if (lrow == 0) { sstat[rb + r][w][0] = m; sstat[rb + r][w][1] = l; }
  }
  __syncthreads();
  if (threadIdx.x < 16) {
    int s = threadIdx.x;
    float m = sstat[s][0][0];
    #pragma unroll
    for (int c = 1; c < 4; ++c) m = fmaxf(m, sstat[s][c][0]);
    float l = 0.f;
    #pragma unroll
    for (int c = 0; c < 4; ++c) l += sstat[s][c][1] * __expf(sstat[s][c][0] - m);
    float* lp = lstats + (((size_t)(b << 4) + s) * 8 + nt) * 2;
    lp[0] = m; lp[1] = l;
  }
}

// ---------------- pv_sm: stats-combine + colnorm (LDS attn) + ax MFMA vs xT ----------------

__global__ __launch_bounds__(256) void pv_sm_k(
    const unsigned short* __restrict__ logits, const float* __restrict__ lstats,
    const unsigned short* __restrict__ xT, unsigned short* __restrict__ A2) {
  __shared__ float s_mi[16][2];
  __shared__ unsigned short s_at[16 * 1032];
  __shared__ unsigned short sA[2][8192];
  const int b_ = blockIdx.y, et = blockIdx.x;
  const int lane = threadIdx.x & 63, w = threadIdx.x >> 6;
  const int lrow = lane & 15, kt = (lane >> 4) << 3;
  const int sr8 = lane >> 3, sc8 = (lane & 7) << 3;
  const unsigned short* lg = logits + ((size_t)b_ << 14);

  // phase 1: combine 8 per-chunk stats
  if (threadIdx.x < 16) {
    int s = threadIdx.x;
    const float* lp = lstats + (((size_t)(b_ << 4) + s) * 8) * 2;
    float m = lp[0];
    #pragma unroll
    for (int c = 1; c < 8; ++c) m = fmaxf(m, lp[c * 2]);
    float l = 0.f;
    #pragma unroll
    for (int c = 0; c < 8; ++c) l += lp[c * 2 + 1] * __expf(lp[c * 2] - m);
    s_mi[s][0] = m; s_mi[s][1] = 1.0f / l;
  }
  __syncthreads();

  // phase 2: column norm -> LDS bf16
  #pragma unroll
  for (int j = 0; j < 4; ++j) {
    int c = threadIdx.x + (j << 8);
    float e[16];
    float cs = 0.f;
    #pragma unroll
    for (int s = 0; s < 16; ++s) {
      e[s] = __expf(bf2f(lg[(size_t)s * 1024 + c]) - s_mi[s][0]) * s_mi[s][1];
      cs += e[s];
    }
    float rv = 1.0f / (cs + 1e-8f);
    #pragma unroll
    for (int s = 0; s < 16; ++s) s_at[s * 1032 + c] = f2bf(e[s] * rv);
  }

  // phase 3: ax^T via MFMA (A = xT stripe, B = attn from LDS)
  const unsigned short* Ab = xT + ((size_t)b_ << 19) + (size_t)(et << 7) * 1024;
  auto stage = [&](int buf, int k0) {
    #pragma unroll
    for (int i = 0; i < 4; ++i) {
      int ii = (w << 2) + i;
      GLD16(Ab + (size_t)((ii << 3) + sr8) * 1024 + k0 + sc8, &sA[buf][ii * 512]);
    }
  };

  f32x4 acc[2];
  acc[0] = f32x4{0.f, 0.f, 0.f, 0.f};
  acc[1] = f32x4{0.f, 0.f, 0.f, 0.f};

  stage(0, 0);
  int cur = 0;
  for (int t = 0; t < 16; ++t) {
    __syncthreads();
    if (t + 1 < 16) stage(cur ^ 1, (t + 1) << 6);
    #pragma unroll
    for (int kk = 0; kk < 2; ++kk) {
      bf16x8 bfv = *reinterpret_cast<const bf16x8*>(&s_at[lrow * 1032 + (t << 6) + (kk << 5) + kt]);
      #pragma unroll
      for (int mi = 0; mi < 2; ++mi) {
        bf16x8 af = *reinterpret_cast<const bf16x8*>(
            &sA[cur][((w * 2 + mi) * 16 + lrow) * 64 + (kk << 5) + kt]);
        acc[mi] = __builtin_amdgcn_mfma_f32_16x16x32_bf16(af, bfv, acc[mi], 0, 0, 0);
      }
    }
    cur ^= 1;
  }

  const int rb = (lane >> 4) << 2;
  const int s = lrow;
  #pragma unroll
  for (int mi = 0; mi < 2; ++mi) {
    int e0 = (et << 7) + (w * 2 + mi) * 16 + rb;
    ushort4 o;
    o.x = f2bf(acc[mi][0]); o.y = f2bf(acc[mi][1]);
    o.z = f2bf(acc[mi][2]); o.w = f2bf(acc[mi][3]);
    *reinterpret_cast<ushort4*>(&A2[(size_t)((b_ << 4) + s) * 1024 + e0]) = o;
  }
}

// ---------------- MFMA GEMM 64x64 (slot-sized GEMMs, BK=64) ----------------

template<int BIAS, int RELU, int ADDSRC, int OUTBF16, int SCALE>
__global__ __launch_bounds__(256) void gemm_sm(
    const unsigned short* __restrict__ A, const unsigned short* __restrict__ W,
    const float* __restrict__ bias, const float* __restrict__ addsrc,
    void* __restrict__ Cout, int M, int N, int K, float scalev) {
  __shared__ unsigned short sA[2][4096];
  __shared__ unsigned short sB[2][4096];
  const int tid = threadIdx.x;
  const int lane = tid & 63, w = tid >> 6;

  int nwg = gridDim.x * gridDim.y;
  int flat = blockIdx.y * gridDim.x + blockIdx.x;
  if ((nwg & 7) == 0) { int c = nwg >> 3; flat = (flat & 7) * c + (flat >> 3); }
  const int row0 = (flat / gridDim.x) << 6;
  const int col0 = (flat % gridDim.x) << 6;

  const int lrow = lane & 15, kt = (lane >> 4) << 3;
  const int sr8 = lane >> 3, sc8 = (lane & 7) << 3;

  f32x4 acc[4];
  #pragma unroll
  for (int m = 0; m < 4; ++m) acc[m] = f32x4{0.f, 0.f, 0.f, 0.f};

  auto stage = [&](int buf, int k0) {
    #pragma unroll
    for (int i = 0; i < 2; ++i) {
      int ii = (w << 1) + i;
      int r = (ii << 3) + sr8;
      GLD16(A + (size_t)(row0 + r) * K + k0 + sc8, &sA[buf][ii * 512]);
      GLD16(W + (size_t)(col0 + r) * K + k0 + sc8, &sB[buf][ii * 512]);
    }
  };

  stage(0, 0);
  const int nt = K >> 6;
  int cur = 0;
  for (int t = 0; t < nt; ++t) {
    __syncthreads();
    if (t + 1 < nt) stage(cur ^ 1, (t + 1) << 6);
    #pragma unroll
    for (int kk = 0; kk < 2; ++kk) {
      bf16x8 bfv = *reinterpret_cast<const bf16x8*>(
          &sB[cur][((w << 4) + lrow) * 64 + (kk << 5) + kt]);
      #pragma unroll
      for (int m = 0; m < 4; ++m) {
        bf16x8 af = *reinterpret_cast<const bf16x8*>(
            &sA[cur][(m * 16 + lrow) * 64 + (kk << 5) + kt]);
        acc[m] = __builtin_amdgcn_mfma_f32_16x16x32_bf16(af, bfv, acc[m], 0, 0, 0);
      }
    }
    cur ^= 1;
  }

  const int rb = (lane >> 4) << 2;
  const int col = col0 + (w << 4) + lrow;
  float bv = BIAS ? bias[col] : 0.0f;
  #pragma unroll
  for (int m = 0; m < 4; ++m) {
    #pragma unroll
    for (int r = 0; r < 4; ++r) {
      int row = row0 + m * 16 + rb + r;
      float v = acc[m][r];
      if (SCALE) v *= scalev;
      v += bv;
      if (ADDSRC) v += addsrc[(size_t)row * N + col];
      if (RELU) v = fmaxf(v, 0.0f);
      if (OUTBF16) ((unsigned short*)Cout)[(size_t)row * N + col] = f2bf(v);
      else ((float*)Cout)[(size_t)row * N + col] = v;
    }
  }
}

// ---------------- host launch ----------------

extern "C" void kernel_launch(void* const* d_in, const int* in_sizes, int n_in,
                              void* d_out, int out_size, void* d_ws, size_t ws_size,
                              hipStream_t stream) {
  const float* inputs  = (const float*)d_in[0];
  const float* noise   = (const float*)d_in[1];
  const float* slot_mu = (const float*)d_in[2];
  const float* slot_ls = (const float*)d_in[3];
  const float* ln_in_g = (const float*)d_in[4];
  const float* ln_in_b = (const float*)d_in[5];
  const float* ln_s_g  = (const float*)d_in[6];
  const float* ln_s_b  = (const float*)d_in[7];
  const float* ln_m_g  = (const float*)d_in[8];
  const float* ln_m_b  = (const float*)d_in[9];
  const float* Wq   = (const float*)d_in[10];
  const float* Wk   = (const float*)d_in[11];
  const float* Wv   = (const float*)d_in[12];
  const float* w_ih = (const float*)d_in[13];
  const float* w_hh = (const float*)d_in[14];
  const float* b_ih = (const float*)d_in[15];
  const float* b_hh = (const float*)d_in[16];
  const float* w1   = (const float*)d_in[17];
  const float* b1   = (const float*)d_in[18];
  const float* w2   = (const float*)d_in[19];
  const float* b2   = (const float*)d_in[20];

  const int BN = 65536, BS = 1024;

  uintptr_t base = (uintptr_t)d_ws;
  auto alloc = [&](size_t bytes) {
    void* p = (void*)base;
    base += (bytes + 255) & ~(size_t)255;
    return p;
  };
  unsigned short* x_bf    = (unsigned short*)alloc((size_t)BN * 512 * 2);
  unsigned short* xT      = (unsigned short*)alloc((size_t)64 * 512 * 1024 * 2);
  unsigned short* wqT     = (unsigned short*)alloc(512 * 512 * 2);
  unsigned short* wkT     = (unsigned short*)alloc(512 * 512 * 2);
  unsigned short* wvT     = (unsigned short*)alloc(512 * 512 * 2);
  unsigned short* wpt     = (unsigned short*)alloc(512 * 512 * 2);
  unsigned short* wih_bf  = (unsigned short*)alloc((size_t)1536 * 512 * 2);
  unsigned short* wcat_bf = (unsigned short*)alloc((size_t)2048 * 1024 * 2);
  float*          bcat    = (float*)alloc(2048 * 4);
  unsigned short* w1_bf   = (unsigned short*)alloc(512 * 512 * 2);
  unsigned short* w2_bf   = (unsigned short*)alloc(512 * 512 * 2);
  float*          slots   = (float*)alloc((size_t)BS * 512 * 4);
  unsigned short* A2      = (unsigned short*)alloc((size_t)BS * 1024 * 2);
  unsigned short* q2_bf   = (unsigned short*)alloc((size_t)BS * 512 * 2);
  unsigned short* logits  = (unsigned short*)alloc((size_t)64 * 16 * 1024 * 2);
  float*          lstats  = (float*)alloc((size_t)64 * 16 * 8 * 2 * 4);
  float*          gates   = (float*)alloc((size_t)BS * 2048 * 4);
  float*          sgru    = (float*)alloc((size_t)BS * 512 * 4);
  unsigned short* lnm_bf  = (unsigned short*)alloc((size_t)BS * 512 * 2);
  unsigned short* h_bf    = (unsigned short*)alloc((size_t)BS * 512 * 2);
  (void)ws_size; (void)n_in; (void)in_sizes; (void)out_size;

  const float scale = 0.044194173824159216f;  // 512^-0.5

  // prologue (6 dispatches)
  wprep_k<<<12296, 256, 0, stream>>>(w1, w2, w_ih, w_hh, b_ih, b_hh,
                                     slot_mu, slot_ls, noise,
                                     w1_bf, w2_bf, wih_bf, wcat_bf, bcat, slots);
  tcast3_k<<<dim3(16, 16, 3), 256, 0, stream>>>(Wq, Wk, Wv, wqT, wkT, wvT);
  gemm_sm<0,0,0,1,1><<<dim3(8, 8), 256, 0, stream>>>(
      wkT, wqT, nullptr, nullptr, wpt, 512, 512, 512, scale);
  gemm_cat<<<dim3(4, 12), 256, 0, stream>>>(
      wih_bf, wvT, wcat_bf, 1536, 512, 512, 1024);
  ln_rows_k<<<16384, 256, 0, stream>>>(inputs, ln_in_g, ln_in_b, x_bf, BN);
  xt_k<<<dim3(16, 8, 64), 256, 0, stream>>>(x_bf, xT);

  for (int it = 0; it < 3; ++it) {
    q2ln_k<<<dim3(4, 64), 256, 0, stream>>>(slots, ln_s_g, ln_s_b, wpt, q2_bf, A2);
    logits_k<<<dim3(8, 64), 256, 0, stream>>>(q2_bf, x_bf, logits, lstats);
    pv_sm_k<<<dim3(4, 64), 256, 0, stream>>>(logits, lstats, xT, A2);
    gemm_sm<1,0,0,0,0><<<dim3(32, 16), 256, 0, stream>>>(
        A2, wcat_bf, bcat, nullptr, gates, BS, 2048, 1024, 1.0f);
    gru_ln_k<<<256, 256, 0, stream>>>(gates, slots, ln_m_g, ln_m_b, sgru, lnm_bf);
    gemm_sm<1,1,0,1,0><<<dim3(8, 16), 256, 0, stream>>>(
        lnm_bf, w1_bf, b1, nullptr, h_bf, BS, 512, 512, 1.0f);
    float* slots_out = (it == 2) ? (float*)d_out : slots;
    gemm_sm<1,0,1,0,0><<<dim3(8, 16), 256, 0, stream>>>(
        h_bf, w2_bf, b2, sgru, slots_out, BS, 512, 512, 1.0f);
  }
}

// Round 13
// 311.037 us; speedup vs baseline: 1.2956x; 1.0367x over previous
//
#include <hip/hip_runtime.h>
#include <hip/hip_bf16.h>
#include <cstdint>
#include <cstddef>

// Shapes fixed: B=64, N=1024, D=512, S=16, 3 iterations.
// Algebra: logits = sn·W'·x^T, W' = scale·Wq^T·Wk   (k never materialized)
//          ax = attn·x;  upd@Wih^T = ax@(Wih·Wv)^T  (v never materialized)
// R13: ln+transpose fused (ln_xt_k); tcast folded into wprep; prologue GEMMs
//      merged (gemm_pre); gates GEMM skips provably-zero K-ranges.

typedef __bf16 bf16x8 __attribute__((ext_vector_type(8)));
typedef float f32x4 __attribute__((ext_vector_type(4)));

__device__ __forceinline__ float bf2f(unsigned int u) {
  union { unsigned int i; float f; } v; v.i = u << 16; return v.f;
}
__device__ __forceinline__ unsigned short f2bf(float x) {
  __hip_bfloat16 h = __float2bfloat16(x);
  unsigned short u;
  __builtin_memcpy(&u, &h, 2);
  return u;
}

#define GLD16(gp, lp)                                                       \
  __builtin_amdgcn_global_load_lds(                                         \
      (const __attribute__((address_space(1))) void*)(gp),                  \
      (__attribute__((address_space(3))) void*)(lp), 16, 0, 0)

// ---------------- merged prep (segmented grid, 13064 blocks) ----------------
// [0,1024) w1 | [1024,2048) w2 | [2048,5120) wih | [5120,7168) wcat rhs top
// [7168,8192) wcat rhs rows[1536,2048) | [8192,10240) wcat zeros
// [10240,10248) bcat | [10248,12296) slots | [12296,13064) transposes Wq/Wk/Wv

__global__ void wprep_k(const float* __restrict__ w1, const float* __restrict__ w2,
                        const float* __restrict__ wih, const float* __restrict__ whh,
                        const float* __restrict__ bih, const float* __restrict__ bhh,
                        const float* __restrict__ mu, const float* __restrict__ ls,
                        const float* __restrict__ noise,
                        const float* __restrict__ Wq, const float* __restrict__ Wk,
                        const float* __restrict__ Wv,
                        unsigned short* __restrict__ w1_bf, unsigned short* __restrict__ w2_bf,
                        unsigned short* __restrict__ wih_bf, unsigned short* __restrict__ wcat,
                        float* __restrict__ bcat, float* __restrict__ slots,
                        unsigned short* __restrict__ wqT, unsigned short* __restrict__ wkT,
                        unsigned short* __restrict__ wvT) {
  __shared__ float tt[32][33];
  int blk = blockIdx.x, t = threadIdx.x;
  if (blk < 1024) {
    int i = blk * 256 + t; w1_bf[i] = f2bf(w1[i]);
  } else if (blk < 2048) {
    int i = (blk - 1024) * 256 + t; w2_bf[i] = f2bf(w2[i]);
  } else if (blk < 5120) {
    int i = (blk - 2048) * 256 + t; wih_bf[i] = f2bf(wih[i]);
  } else if (blk < 7168) {
    int i = (blk - 5120) * 256 + t;
    int j = i >> 9, d = i & 511;
    wcat[(size_t)j * 1024 + 512 + d] = f2bf(whh[(size_t)j * 512 + d]);
  } else if (blk < 8192) {
    int i = (blk - 7168) * 256 + t;
    int j = i >> 9, d = i & 511;
    wcat[(size_t)(1536 + j) * 1024 + 512 + d] = f2bf(whh[(size_t)(1024 + j) * 512 + d]);
  } else if (blk < 10240) {
    int i = (blk - 8192) * 256 + t;
    if (i < 262144) {
      int j = i >> 9, d = i & 511;
      wcat[(size_t)(1536 + j) * 1024 + d] = 0;
    } else {
      int k = i - 262144;
      int j = k >> 9, d = k & 511;
      wcat[(size_t)(1024 + j) * 1024 + 512 + d] = 0;
    }
  } else if (blk < 10248) {
    int j = (blk - 10240) * 256 + t;
    float v;
    if (j < 1024)      v = bih[j] + bhh[j];
    else if (j < 1536) v = bih[j];
    else               v = bhh[j - 512];
    bcat[j] = v;
  } else if (blk < 12296) {
    int i = (blk - 10248) * 256 + t;
    int d = i & 511;
    slots[i] = mu[d] + expf(ls[d]) * noise[i];
  } else {
    int blk2 = blk - 12296;              // 768 transpose blocks
    int mat = blk2 >> 8, tile = blk2 & 255;
    const float* in = mat == 0 ? Wq : (mat == 1 ? Wk : Wv);
    unsigned short* out = mat == 0 ? wqT : (mat == 1 ? wkT : wvT);
    int c0 = (tile & 15) << 5, r0 = (tile >> 4) << 5;
    int tx = t & 31, ty = t >> 5;
    #pragma unroll
    for (int i = 0; i < 4; ++i)
      tt[ty + 8 * i][tx] = in[(size_t)(r0 + ty + 8 * i) * 512 + c0 + tx];
    __syncthreads();
    #pragma unroll
    for (int i = 0; i < 4; ++i)
      out[(size_t)(c0 + ty + 8 * i) * 512 + r0 + tx] = f2bf(tt[tx][ty + 8 * i]);
  }
}

// ---------------- ln_xt: LN(inputs) -> x_bf AND xT (fused) ----------------
// grid 2048 blocks, 32 rows each (blocks never straddle batches), LDS 33KB.

__global__ __launch_bounds__(256) void ln_xt_k(
    const float* __restrict__ in, const float* __restrict__ g, const float* __restrict__ b,
    unsigned short* __restrict__ x_bf, unsigned short* __restrict__ xT) {
  __shared__ unsigned short tbuf[32 * 520];
  const int row0 = blockIdx.x << 5;
  const int bb_ = row0 >> 10;
  const int n0 = row0 & 1023;
  const int w = threadIdx.x >> 6, lane = threadIdx.x & 63;

  const float4* gp = reinterpret_cast<const float4*>(g);
  const float4* bp = reinterpret_cast<const float4*>(b);
  float4 g0 = gp[lane], g1 = gp[lane + 64];
  float4 b0 = bp[lane], b1 = bp[lane + 64];

  #pragma unroll
  for (int i = 0; i < 8; ++i) {
    int r = (w << 3) + i;
    int row = row0 + r;
    const float4* rp = reinterpret_cast<const float4*>(in + (size_t)row * 512);
    float4 v0 = rp[lane], v1 = rp[lane + 64];
    float s = v0.x + v0.y + v0.z + v0.w + v1.x + v1.y + v1.z + v1.w;
    float q = v0.x*v0.x + v0.y*v0.y + v0.z*v0.z + v0.w*v0.w
            + v1.x*v1.x + v1.y*v1.y + v1.z*v1.z + v1.w*v1.w;
    #pragma unroll
    for (int o = 32; o > 0; o >>= 1) { s += __shfl_xor(s, o); q += __shfl_xor(q, o); }
    float m = s * (1.0f / 512.0f);
    float rstd = rsqrtf(q * (1.0f / 512.0f) - m * m + 1e-8f);
    ushort4 o0, o1;
    o0.x = f2bf((v0.x - m) * rstd * g0.x + b0.x);
    o0.y = f2bf((v0.y - m) * rstd * g0.y + b0.y);
    o0.z = f2bf((v0.z - m) * rstd * g0.z + b0.z);
    o0.w = f2bf((v0.w - m) * rstd * g0.w + b0.w);
    o1.x = f2bf((v1.x - m) * rstd * g1.x + b1.x);
    o1.y = f2bf((v1.y - m) * rstd * g1.y + b1.y);
    o1.z = f2bf((v1.z - m) * rstd * g1.z + b1.z);
    o1.w = f2bf((v1.w - m) * rstd * g1.w + b1.w);
    ushort4* op = reinterpret_cast<ushort4*>(x_bf + (size_t)row * 512);
    op[lane] = o0; op[lane + 64] = o1;
    *reinterpret_cast<ushort4*>(&tbuf[r * 520 + lane * 4]) = o0;
    *reinterpret_cast<ushort4*>(&tbuf[r * 520 + 256 + lane * 4]) = o1;
  }
  __syncthreads();

  // transpose: xT[b][e][n0..n0+31]
  const int e_lo = threadIdx.x >> 2;          // 0..63
  const int n8 = (threadIdx.x & 3) << 3;      // 0,8,16,24
  #pragma unroll
  for (int et = 0; et < 8; ++et) {
    int e = (et << 6) + e_lo;
    ushort4 a, c;
    #pragma unroll
    for (int j = 0; j < 4; ++j) ((unsigned short*)&a)[j] = tbuf[(n8 + j) * 520 + e];
    #pragma unroll
    for (int j = 0; j < 4; ++j) ((unsigned short*)&c)[j] = tbuf[(n8 + 4 + j) * 520 + e];
    unsigned short* o = xT + ((size_t)(bb_ << 9) + e) * 1024 + n0 + n8;
    *reinterpret_cast<ushort4*>(o) = a;
    *reinterpret_cast<ushort4*>(o + 4) = c;
  }
}

// GRU (fused-gates layout) + LN
__global__ __launch_bounds__(256) void gru_ln_k(
    const float* __restrict__ gates, const float* __restrict__ hp,
    const float* __restrict__ g, const float* __restrict__ b,
    float* __restrict__ sgru, unsigned short* __restrict__ lnm) {
  int w = threadIdx.x >> 6, lane = threadIdx.x & 63;
  int row = (blockIdx.x << 2) + w;
  size_t gb = (size_t)row * 2048 + (lane << 3);
  size_t hb = (size_t)row * 512 + (lane << 3);
  float rs[8], zs[8], in_[8], hn[8], hv[8], y[8];
  #pragma unroll
  for (int c = 0; c < 2; ++c) {
    *reinterpret_cast<float4*>(rs + 4*c)  = *reinterpret_cast<const float4*>(gates + gb + 4*c);
    *reinterpret_cast<float4*>(zs + 4*c)  = *reinterpret_cast<const float4*>(gates + gb + 512 + 4*c);
    *reinterpret_cast<float4*>(in_ + 4*c) = *reinterpret_cast<const float4*>(gates + gb + 1024 + 4*c);
    *reinterpret_cast<float4*>(hn + 4*c)  = *reinterpret_cast<const float4*>(gates + gb + 1536 + 4*c);
    *reinterpret_cast<float4*>(hv + 4*c)  = *reinterpret_cast<const float4*>(hp + hb + 4*c);
  }
  float s = 0.f, q = 0.f;
  #pragma unroll
  for (int j = 0; j < 8; ++j) {
    float r = 1.0f / (1.0f + expf(-rs[j]));
    float z = 1.0f / (1.0f + expf(-zs[j]));
    float n = tanhf(in_[j] + r * hn[j]);
    float h = (1.0f - z) * n + z * hv[j];
    y[j] = h; s += h; q += h * h;
  }
  #pragma unroll
  for (int o = 32; o > 0; o >>= 1) { s += __shfl_xor(s, o); q += __shfl_xor(q, o); }
  float m = s * (1.0f / 512.0f);
  float rstd = rsqrtf(q * (1.0f / 512.0f) - m * m + 1e-8f);
  const float* gg = g + (lane << 3);
  const float* bb = b + (lane << 3);
  #pragma unroll
  for (int c = 0; c < 2; ++c)
    *reinterpret_cast<float4*>(sgru + hb + 4*c) = *reinterpret_cast<const float4*>(y + 4*c);
  uint4 o4;
  unsigned int p[8];
  #pragma unroll
  for (int j = 0; j < 8; ++j) p[j] = f2bf((y[j] - m) * rstd * gg[j] + bb[j]);
  o4.x = p[0] | (p[1] << 16); o4.y = p[2] | (p[3] << 16);
  o4.z = p[4] | (p[5] << 16); o4.w = p[6] | (p[7] << 16);
  *reinterpret_cast<uint4*>(lnm + hb) = o4;
}

// ---------------- gemm_pre: 64 blocks = gemm_cat(48) + W'T gemm(16), 128x128, BK=64 ----------------
// blocks [0,48): wcat[j][0..512) = bf16(wih @ wvT^T), ldc 1024, M=1536,N=512
// blocks [48,64): wpt = scale * (wkT @ wqT^T), ldc 512, M=N=512

__global__ __launch_bounds__(256) void gemm_pre(
    const unsigned short* __restrict__ wih_bf, const unsigned short* __restrict__ wvT,
    const unsigned short* __restrict__ wkT, const unsigned short* __restrict__ wqT,
    unsigned short* __restrict__ wcat, unsigned short* __restrict__ wpt, float scale) {
  __shared__ unsigned short sA[2][8192];
  __shared__ unsigned short sB[2][8192];
  const int blk = blockIdx.x;
  const int lane = threadIdx.x & 63, w = threadIdx.x >> 6;

  const unsigned short *A, *W;
  unsigned short* C;
  int row0, col0, ldc;
  float sc;
  if (blk < 48) {
    A = wih_bf; W = wvT; C = wcat; ldc = 1024; sc = 1.0f;
    row0 = (blk >> 2) << 7; col0 = (blk & 3) << 7;
  } else {
    A = wkT; W = wqT; C = wpt; ldc = 512; sc = scale;
    int f = blk - 48;
    row0 = (f >> 2) << 7; col0 = (f & 3) << 7;
  }
  const int K = 512;

  const int wm = (w >> 1) << 6, wn = (w & 1) << 6;
  const int lrow = lane & 15, kt = (lane >> 4) << 3;
  const int sr8 = lane >> 3, sc8 = (lane & 7) << 3;

  f32x4 acc[4][4];
  #pragma unroll
  for (int m = 0; m < 4; ++m)
    #pragma unroll
    for (int n = 0; n < 4; ++n) acc[m][n] = f32x4{0.f, 0.f, 0.f, 0.f};

  auto stage = [&](int buf, int k0) {
    #pragma unroll
    for (int i = 0; i < 4; ++i) {
      int ii = (w << 2) + i;
      int r = (ii << 3) + sr8;
      GLD16(A + (size_t)(row0 + r) * K + k0 + sc8, &sA[buf][ii * 512]);
      GLD16(W + (size_t)(col0 + r) * K + k0 + sc8, &sB[buf][ii * 512]);
    }
  };

  stage(0, 0);
  int cur = 0;
  for (int t = 0; t < 8; ++t) {
    __syncthreads();
    if (t + 1 < 8) stage(cur ^ 1, (t + 1) << 6);
    #pragma unroll
    for (int kk = 0; kk < 2; ++kk) {
      bf16x8 af[4], bfv[4];
      #pragma unroll
      for (int m = 0; m < 4; ++m)
        af[m] = *reinterpret_cast<const bf16x8*>(&sA[cur][(wm + m * 16 + lrow) * 64 + (kk << 5) + kt]);
      #pragma unroll
      for (int n = 0; n < 4; ++n)
        bfv[n] = *reinterpret_cast<const bf16x8*>(&sB[cur][(wn + n * 16 + lrow) * 64 + (kk << 5) + kt]);
      #pragma unroll
      for (int m = 0; m < 4; ++m)
        #pragma unroll
        for (int n = 0; n < 4; ++n)
          acc[m][n] = __builtin_amdgcn_mfma_f32_16x16x32_bf16(af[m], bfv[n], acc[m][n], 0, 0, 0);
    }
    cur ^= 1;
  }

  const int rb = (lane >> 4) << 2;
  #pragma unroll
  for (int m = 0; m < 4; ++m) {
    #pragma unroll
    for (int n = 0; n < 4; ++n) {
      int col = col0 + wn + n * 16 + lrow;
      #pragma unroll
      for (int r = 0; r < 4; ++r) {
        int row = row0 + wm + m * 16 + rb + r;
        C[(size_t)row * ldc + col] = f2bf(acc[m][n][r] * sc);
      }
    }
  }
}

// ---------------- q2ln: LN(slots_b) in LDS, then q2 = sn @ W' tile (BK=64) ----------------

__global__ __launch_bounds__(256) void q2ln_k(
    const float* __restrict__ slots, const float* __restrict__ g, const float* __restrict__ b,
    const unsigned short* __restrict__ wpt, unsigned short* __restrict__ q2,
    unsigned short* __restrict__ A2) {
  __shared__ unsigned short s_sn[16 * 520];
  __shared__ unsigned short sB[2][8192];
  const int b_ = blockIdx.y, ct = blockIdx.x;
  const int lane = threadIdx.x & 63, w = threadIdx.x >> 6;
  const int lrow = lane & 15, kt = (lane >> 4) << 3;
  const int sr8 = lane >> 3, sc8 = (lane & 7) << 3;

  const float4* gp = reinterpret_cast<const float4*>(g);
  const float4* bp = reinterpret_cast<const float4*>(b);
  float4 g0 = gp[lane], g1 = gp[lane + 64];
  float4 b0 = bp[lane], b1 = bp[lane + 64];
  #pragma unroll
  for (int rr = 0; rr < 4; ++rr) {
    int r = w * 4 + rr;
    const float4* rp = reinterpret_cast<const float4*>(slots + (size_t)(b_ * 16 + r) * 512);
    float4 v0 = rp[lane], v1 = rp[lane + 64];
    float s = v0.x + v0.y + v0.z + v0.w + v1.x + v1.y + v1.z + v1.w;
    float q = v0.x*v0.x + v0.y*v0.y + v0.z*v0.z + v0.w*v0.w
            + v1.x*v1.x + v1.y*v1.y + v1.z*v1.z + v1.w*v1.w;
    #pragma unroll
    for (int o = 32; o > 0; o >>= 1) { s += __shfl_xor(s, o); q += __shfl_xor(q, o); }
    float m = s * (1.0f / 512.0f);
    float rstd = rsqrtf(q * (1.0f / 512.0f) - m * m + 1e-8f);
    ushort4 o0, o1;
    o0.x = f2bf((v0.x - m) * rstd * g0.x + b0.x);
    o0.y = f2bf((v0.y - m) * rstd * g0.y + b0.y);
    o0.z = f2bf((v0.z - m) * rstd * g0.z + b0.z);
    o0.w = f2bf((v0.w - m) * rstd * g0.w + b0.w);
    o1.x = f2bf((v1.x - m) * rstd * g1.x + b1.x);
    o1.y = f2bf((v1.y - m) * rstd * g1.y + b1.y);
    o1.z = f2bf((v1.z - m) * rstd * g1.z + b1.z);
    o1.w = f2bf((v1.w - m) * rstd * g1.w + b1.w);
    *reinterpret_cast<ushort4*>(&s_sn[r * 520 + lane * 4]) = o0;
    *reinterpret_cast<ushort4*>(&s_sn[r * 520 + 256 + lane * 4]) = o1;
    if (ct == 0) {
      ushort4 c0, c1;
      c0.x = f2bf(v0.x); c0.y = f2bf(v0.y); c0.z = f2bf(v0.z); c0.w = f2bf(v0.w);
      c1.x = f2bf(v1.x); c1.y = f2bf(v1.y); c1.z = f2bf(v1.z); c1.w = f2bf(v1.w);
      unsigned short* a2r = A2 + (size_t)(b_ * 16 + r) * 1024 + 512;
      *reinterpret_cast<ushort4*>(a2r + lane * 4) = c0;
      *reinterpret_cast<ushort4*>(a2r + 256 + lane * 4) = c1;
    }
  }

  const unsigned short* Bb = wpt + (size_t)(ct << 7) * 512;
  auto stage = [&](int buf, int k0) {
    #pragma unroll
    for (int i = 0; i < 4; ++i) {
      int ii = (w << 2) + i;
      GLD16(Bb + (size_t)((ii << 3) + sr8) * 512 + k0 + sc8, &sB[buf][ii * 512]);
    }
  };

  f32x4 acc[2];
  acc[0] = f32x4{0.f, 0.f, 0.f, 0.f};
  acc[1] = f32x4{0.f, 0.f, 0.f, 0.f};

  stage(0, 0);
  int cur = 0;
  for (int t = 0; t < 8; ++t) {
    __syncthreads();
    if (t + 1 < 8) stage(cur ^ 1, (t + 1) << 6);
    #pragma unroll
    for (int kk = 0; kk < 2; ++kk) {
      bf16x8 af = *reinterpret_cast<const bf16x8*>(&s_sn[lrow * 520 + (t << 6) + (kk << 5) + kt]);
      #pragma unroll
      for (int ni = 0; ni < 2; ++ni) {
        bf16x8 bfv = *reinterpret_cast<const bf16x8*>(
            &sB[cur][((w * 2 + ni) * 16 + lrow) * 64 + (kk << 5) + kt]);
        acc[ni] = __builtin_amdgcn_mfma_f32_16x16x32_bf16(af, bfv, acc[ni], 0, 0, 0);
      }
    }
    cur ^= 1;
  }

  const int rb = (lane >> 4) << 2;
  #pragma unroll
  for (int ni = 0; ni < 2; ++ni) {
    int col = (ct << 7) + (w * 2 + ni) * 16 + lrow;
    #pragma unroll
    for (int r = 0; r < 4; ++r) {
      int s = rb + r;
      q2[(size_t)((b_ << 4) + s) * 512 + col] = f2bf(acc[ni][r]);
    }
  }
}

// ---------------- logits + per-chunk softmax stats (bf16 out, BK=64) ----------------

__global__ __launch_bounds__(256) void logits_k(
    const unsigned short* __restrict__ q2, const unsigned short* __restrict__ x,
    unsigned short* __restrict__ out, float* __restrict__ lstats) {
  __shared__ unsigned short sA[2][1024];
  __shared__ unsigned short sB[2][8192];
  __shared__ float sstat[16][4][2];
  const int b = blockIdx.y, nt = blockIdx.x;
  const int lane = threadIdx.x & 63, w = threadIdx.x >> 6;
  const int lrow = lane & 15, kt = (lane >> 4) << 3;
  const int sr8 = lane >> 3, sc8 = (lane & 7) << 3;
  const unsigned short* Ab = q2 + ((size_t)b << 13);
  const unsigned short* Bb = x + (((size_t)(b << 10) + (nt << 7)) << 9);

  f32x4 acc[2];
  acc[0] = f32x4{0.f, 0.f, 0.f, 0.f};
  acc[1] = f32x4{0.f, 0.f, 0.f, 0.f};

  auto stage = [&](int buf, int k0) {
    #pragma unroll
    for (int i = 0; i < 4; ++i) {
      int ii = (w << 2) + i;
      GLD16(Bb + (size_t)((ii << 3) + sr8) * 512 + k0 + sc8, &sB[buf][ii * 512]);
    }
    if (w == 0) {
      #pragma unroll
      for (int i = 0; i < 2; ++i)
        GLD16(Ab + (size_t)((i << 3) + sr8) * 512 + k0 + sc8, &sA[buf][i * 512]);
    }
  };

  stage(0, 0);
  int cur = 0;
  for (int t = 0; t < 8; ++t) {
    __syncthreads();
    if (t + 1 < 8) stage(cur ^ 1, (t + 1) << 6);
    #pragma unroll
    for (int kk = 0; kk < 2; ++kk) {
      bf16x8 af = *reinterpret_cast<const bf16x8*>(&sA[cur][lrow * 64 + (kk << 5) + kt]);
      #pragma unroll
      for (int ni = 0; ni < 2; ++ni) {
        bf16x8 bfv = *reinterpret_cast<const bf16x8*>(
            &sB[cur][((w * 2 + ni) * 16 + lrow) * 64 + (kk << 5) + kt]);
        acc[ni] = __builtin_amdgcn_mfma_f32_16x16x32_bf16(af, bfv, acc[ni], 0, 0, 0);
      }
    }
    cur ^= 1;
  }

  const int rb = (lane >> 4) << 2;
  unsigned short lv[2][4];
  #pragma unroll
  for (int ni = 0; ni < 2; ++ni) {
    int n = (nt << 7) + (w * 2 + ni) * 16 + lrow;
    #pragma unroll
    for (int r = 0; r < 4; ++r) {
      unsigned short u = f2bf(acc[ni][r]);
      lv[ni][r] = u;
      out[(size_t)((b << 4) + rb + r) * 1024 + n] = u;
    }
  }
  #pragma unroll
  for (int r = 0; r < 4; ++r) {
    float v0 = bf2f(lv[0][r]), v1 = bf2f(lv[1][r]);
    float m = fmaxf(v0, v1);
    #pragma unroll
    for (int o = 1; o < 16; o <<= 1) m = fmaxf(m, __shfl_xor(m, o));
    float l = __expf(v0 - m) + __expf(v1 - m);
    #pragma unroll
    for (int o = 1; o < 16; o <<= 1) l += __shfl_xor(l, o);
    if (lrow == 0) { sstat[rb + r][w][0] = m; sstat[rb + r][w][1] = l; }
  }
  __syncthreads();
  if (threadIdx.x < 16) {
    int s = threadIdx.x;
    float m = sstat[s][0][0];
    #pragma unroll
    for (int c = 1; c < 4; ++c) m = fmaxf(m, sstat[s][c][0]);
    float l = 0.f;
    #pragma unroll
    for (int c = 0; c < 4; ++c) l += sstat[s][c][1] * __expf(sstat[s][c][0] - m);
    float* lp = lstats + (((size_t)(b << 4) + s) * 8 + nt) * 2;
    lp[0] = m; lp[1] = l;
  }
}

// ---------------- pv_sm: stats-combine + colnorm (LDS attn) + ax MFMA vs xT ----------------

__global__ __launch_bounds__(256) void pv_sm_k(
    const unsigned short* __restrict__ logits, const float* __restrict__ lstats,
    const unsigned short* __restrict__ xT, unsigned short* __restrict__ A2) {
  __shared__ float s_mi[16][2];
  __shared__ unsigned short s_at[16 * 1032];
  __shared__ unsigned short sA[2][8192];
  const int b_ = blockIdx.y, et = blockIdx.x;
  const int lane = threadIdx.x & 63, w = threadIdx.x >> 6;
  const int lrow = lane & 15, kt = (lane >> 4) << 3;
  const int sr8 = lane >> 3, sc8 = (lane & 7) << 3;
  const unsigned short* lg = logits + ((size_t)b_ << 14);

  if (threadIdx.x < 16) {
    int s = threadIdx.x;
    const float* lp = lstats + (((size_t)(b_ << 4) + s) * 8) * 2;
    float m = lp[0];
    #pragma unroll
    for (int c = 1; c < 8; ++c) m = fmaxf(m, lp[c * 2]);
    float l = 0.f;
    #pragma unroll
    for (int c = 0; c < 8; ++c) l += lp[c * 2 + 1] * __expf(lp[c * 2] - m);
    s_mi[s][0] = m; s_mi[s][1] = 1.0f / l;
  }
  __syncthreads();

  #pragma unroll
  for (int j = 0; j < 4; ++j) {
    int c = threadIdx.x + (j << 8);
    float e[16];
    float cs = 0.f;
    #pragma unroll
    for (int s = 0; s < 16; ++s) {
      e[s] = __expf(bf2f(lg[(size_t)s * 1024 + c]) - s_mi[s][0]) * s_mi[s][1];
      cs += e[s];
    }
    float rv = 1.0f / (cs + 1e-8f);
    #pragma unroll
    for (int s = 0; s < 16; ++s) s_at[s * 1032 + c] = f2bf(e[s] * rv);
  }

  const unsigned short* Ab = xT + ((size_t)b_ << 19) + (size_t)(et << 7) * 1024;
  auto stage = [&](int buf, int k0) {
    #pragma unroll
    for (int i = 0; i < 4; ++i) {
      int ii = (w << 2) + i;
      GLD16(Ab + (size_t)((ii << 3) + sr8) * 1024 + k0 + sc8, &sA[buf][ii * 512]);
    }
  };

  f32x4 acc[2];
  acc[0] = f32x4{0.f, 0.f, 0.f, 0.f};
  acc[1] = f32x4{0.f, 0.f, 0.f, 0.f};

  stage(0, 0);
  int cur = 0;
  for (int t = 0; t < 16; ++t) {
    __syncthreads();
    if (t + 1 < 16) stage(cur ^ 1, (t + 1) << 6);
    #pragma unroll
    for (int kk = 0; kk < 2; ++kk) {
      bf16x8 bfv = *reinterpret_cast<const bf16x8*>(&s_at[lrow * 1032 + (t << 6) + (kk << 5) + kt]);
      #pragma unroll
      for (int mi = 0; mi < 2; ++mi) {
        bf16x8 af = *reinterpret_cast<const bf16x8*>(
            &sA[cur][((w * 2 + mi) * 16 + lrow) * 64 + (kk << 5) + kt]);
        acc[mi] = __builtin_amdgcn_mfma_f32_16x16x32_bf16(af, bfv, acc[mi], 0, 0, 0);
      }
    }
    cur ^= 1;
  }

  const int rb = (lane >> 4) << 2;
  const int s = lrow;
  #pragma unroll
  for (int mi = 0; mi < 2; ++mi) {
    int e0 = (et << 7) + (w * 2 + mi) * 16 + rb;
    ushort4 o;
    o.x = f2bf(acc[mi][0]); o.y = f2bf(acc[mi][1]);
    o.z = f2bf(acc[mi][2]); o.w = f2bf(acc[mi][3]);
    *reinterpret_cast<ushort4*>(&A2[(size_t)((b_ << 4) + s) * 1024 + e0]) = o;
  }
}

// ---------------- MFMA GEMM 64x64 (slot-sized GEMMs, BK=64) ----------------
// GATES=1: N=2048 gates GEMM; cols [1024,1536) use K=[0,512), [1536,2048) K=[512,1024)
// (the skipped ranges multiply exactly-zero weights -> bit-identical).

template<int BIAS, int RELU, int ADDSRC, int OUTBF16, int GATES>
__global__ __launch_bounds__(256) void gemm_sm(
    const unsigned short* __restrict__ A, const unsigned short* __restrict__ W,
    const float* __restrict__ bias, const float* __restrict__ addsrc,
    void* __restrict__ Cout, int M, int N, int K) {
  __shared__ unsigned short sA[2][4096];
  __shared__ unsigned short sB[2][4096];
  const int tid = threadIdx.x;
  const int lane = tid & 63, w = tid >> 6;

  int nwg = gridDim.x * gridDim.y;
  int flat = blockIdx.y * gridDim.x + blockIdx.x;
  if ((nwg & 7) == 0) { int c = nwg >> 3; flat = (flat & 7) * c + (flat >> 3); }
  const int row0 = (flat / gridDim.x) << 6;
  const int col0 = (flat % gridDim.x) << 6;

  int kb = 0, ke = K;
  if (GATES) {
    if (col0 >= 1536)      { kb = 512; ke = 1024; }
    else if (col0 >= 1024) { kb = 0;   ke = 512;  }
  }

  const int lrow = lane & 15, kt = (lane >> 4) << 3;
  const int sr8 = lane >> 3, sc8 = (lane & 7) << 3;

  f32x4 acc[4];
  #pragma unroll
  for (int m = 0; m < 4; ++m) acc[m] = f32x4{0.f, 0.f, 0.f, 0.f};

  auto stage = [&](int buf, int k0) {
    #pragma unroll
    for (int i = 0; i < 2; ++i) {
      int ii = (w << 1) + i;
      int r = (ii << 3) + sr8;
      GLD16(A + (size_t)(row0 + r) * K + k0 + sc8, &sA[buf][ii * 512]);
      GLD16(W + (size_t)(col0 + r) * K + k0 + sc8, &sB[buf][ii * 512]);
    }
  };

  stage(0, kb);
  const int nt = (ke - kb) >> 6;
  int cur = 0;
  for (int t = 0; t < nt; ++t) {
    __syncthreads();
    if (t + 1 < nt) stage(cur ^ 1, kb + ((t + 1) << 6));
    #pragma unroll
    for (int kk = 0; kk < 2; ++kk) {
      bf16x8 bfv = *reinterpret_cast<const bf16x8*>(
          &sB[cur][((w << 4) + lrow) * 64 + (kk << 5) + kt]);
      #pragma unroll
      for (int m = 0; m < 4; ++m) {
        bf16x8 af = *reinterpret_cast<const bf16x8*>(
            &sA[cur][(m * 16 + lrow) * 64 + (kk << 5) + kt]);
        acc[m] = __builtin_amdgcn_mfma_f32_16x16x32_bf16(af, bfv, acc[m], 0, 0, 0);
      }
    }
    cur ^= 1;
  }

  const int rb = (lane >> 4) << 2;
  const int col = col0 + (w << 4) + lrow;
  float bv = BIAS ? bias[col] : 0.0f;
  #pragma unroll
  for (int m = 0; m < 4; ++m) {
    #pragma unroll
    for (int r = 0; r < 4; ++r) {
      int row = row0 + m * 16 + rb + r;
      float v = acc[m][r] + bv;
      if (ADDSRC) v += addsrc[(size_t)row * N + col];
      if (RELU) v = fmaxf(v, 0.0f);
      if (OUTBF16) ((unsigned short*)Cout)[(size_t)row * N + col] = f2bf(v);
      else ((float*)Cout)[(size_t)row * N + col] = v;
    }
  }
}

// ---------------- host launch ----------------

extern "C" void kernel_launch(void* const* d_in, const int* in_sizes, int n_in,
                              void* d_out, int out_size, void* d_ws, size_t ws_size,
                              hipStream_t stream) {
  const float* inputs  = (const float*)d_in[0];
  const float* noise   = (const float*)d_in[1];
  const float* slot_mu = (const float*)d_in[2];
  const float* slot_ls = (const float*)d_in[3];
  const float* ln_in_g = (const float*)d_in[4];
  const float* ln_in_b = (const float*)d_in[5];
  const float* ln_s_g  = (const float*)d_in[6];
  const float* ln_s_b  = (const float*)d_in[7];
  const float* ln_m_g  = (const float*)d_in[8];
  const float* ln_m_b  = (const float*)d_in[9];
  const float* Wq   = (const float*)d_in[10];
  const float* Wk   = (const float*)d_in[11];
  const float* Wv   = (const float*)d_in[12];
  const float* w_ih = (const float*)d_in[13];
  const float* w_hh = (const float*)d_in[14];
  const float* b_ih = (const float*)d_in[15];
  const float* b_hh = (const float*)d_in[16];
  const float* w1   = (const float*)d_in[17];
  const float* b1   = (const float*)d_in[18];
  const float* w2   = (const float*)d_in[19];
  const float* b2   = (const float*)d_in[20];

  const int BN = 65536, BS = 1024;

  uintptr_t base = (uintptr_t)d_ws;
  auto alloc = [&](size_t bytes) {
    void* p = (void*)base;
    base += (bytes + 255) & ~(size_t)255;
    return p;
  };
  unsigned short* x_bf    = (unsigned short*)alloc((size_t)BN * 512 * 2);
  unsigned short* xT      = (unsigned short*)alloc((size_t)64 * 512 * 1024 * 2);
  unsigned short* wqT     = (unsigned short*)alloc(512 * 512 * 2);
  unsigned short* wkT     = (unsigned short*)alloc(512 * 512 * 2);
  unsigned short* wvT     = (unsigned short*)alloc(512 * 512 * 2);
  unsigned short* wpt     = (unsigned short*)alloc(512 * 512 * 2);
  unsigned short* wih_bf  = (unsigned short*)alloc((size_t)1536 * 512 * 2);
  unsigned short* wcat_bf = (unsigned short*)alloc((size_t)2048 * 1024 * 2);
  float*          bcat    = (float*)alloc(2048 * 4);
  unsigned short* w1_bf   = (unsigned short*)alloc(512 * 512 * 2);
  unsigned short* w2_bf   = (unsigned short*)alloc(512 * 512 * 2);
  float*          slots   = (float*)alloc((size_t)BS * 512 * 4);
  unsigned short* A2      = (unsigned short*)alloc((size_t)BS * 1024 * 2);
  unsigned short* q2_bf   = (unsigned short*)alloc((size_t)BS * 512 * 2);
  unsigned short* logits  = (unsigned short*)alloc((size_t)64 * 16 * 1024 * 2);
  float*          lstats  = (float*)alloc((size_t)64 * 16 * 8 * 2 * 4);
  float*          gates   = (float*)alloc((size_t)BS * 2048 * 4);
  float*          sgru    = (float*)alloc((size_t)BS * 512 * 4);
  unsigned short* lnm_bf  = (unsigned short*)alloc((size_t)BS * 512 * 2);
  unsigned short* h_bf    = (unsigned short*)alloc((size_t)BS * 512 * 2);
  (void)ws_size; (void)n_in; (void)in_sizes; (void)out_size;

  const float scale = 0.044194173824159216f;  // 512^-0.5

  // prologue (3 dispatches)
  wprep_k<<<13064, 256, 0, stream>>>(w1, w2, w_ih, w_hh, b_ih, b_hh,
                                     slot_mu, slot_ls, noise, Wq, Wk, Wv,
                                     w1_bf, w2_bf, wih_bf, wcat_bf, bcat, slots,
                                     wqT, wkT, wvT);
  gemm_pre<<<64, 256, 0, stream>>>(wih_bf, wvT, wkT, wqT, wcat_bf, wpt, scale);
  ln_xt_k<<<2048, 256, 0, stream>>>(inputs, ln_in_g, ln_in_b, x_bf, xT);

  for (int it = 0; it < 3; ++it) {
    q2ln_k<<<dim3(4, 64), 256, 0, stream>>>(slots, ln_s_g, ln_s_b, wpt, q2_bf, A2);
    logits_k<<<dim3(8, 64), 256, 0, stream>>>(q2_bf, x_bf, logits, lstats);
    pv_sm_k<<<dim3(4, 64), 256, 0, stream>>>(logits, lstats, xT, A2);
    gemm_sm<1,0,0,0,1><<<dim3(32, 16), 256, 0, stream>>>(
        A2, wcat_bf, bcat, nullptr, gates, BS, 2048, 1024);
    gru_ln_k<<<256, 256, 0, stream>>>(gates, slots, ln_m_g, ln_m_b, sgru, lnm_bf);
    gemm_sm<1,1,0,1,0><<<dim3(8, 16), 256, 0, stream>>>(
        lnm_bf, w1_bf, b1, nullptr, h_bf, BS, 512, 512);
    float* slots_out = (it == 2) ? (float*)d_out : slots;
    gemm_sm<1,0,1,0,0><<<dim3(8, 16), 256, 0, stream>>>(
        h_bf, w2_bf, b2, sgru, slots_out, BS, 512, 512);
  }
}